// Round 1
// 476.526 us; speedup vs baseline: 1.5448x; 1.5448x over previous
//
#include <hip/hip_runtime.h>
#include <stdint.h>

#define B_ 2
#define T_ 1024
#define C_ 2048
#define H_ 16
#define D_ 128
#define P_ 1024
#define L_ 2048   // P + T
#define M_ 2048   // B*T

typedef unsigned short u16;
typedef __attribute__((ext_vector_type(8))) short short8;   // MFMA A/B frag (8 bf16)
typedef __attribute__((ext_vector_type(4))) float f32x4;    // MFMA C/D frag
typedef __attribute__((ext_vector_type(8))) u16 u16x8;      // 16B vector
typedef __attribute__((ext_vector_type(4))) u16 u16x4;      // 8B vector

__device__ __forceinline__ u16 f2bf(float x) {
    union { float f; uint32_t u; } c; c.f = x;
    uint32_t u = c.u;
    return (u16)((u + 0x7fffu + ((u >> 16) & 1u)) >> 16);   // RNE
}

// Async global->LDS, 16B per lane. LDS dest = uniform base + lane*16 (HW rule).
__device__ __forceinline__ void gload_lds16(const void* g, void* l) {
    typedef __attribute__((address_space(1))) const void gvoid;
    typedef __attribute__((address_space(3))) void lvoid;
    __builtin_amdgcn_global_load_lds((gvoid*)g, (lvoid*)l, 16, 0, 0);
}

// ---------------------------------------------------------------------------
// f32 -> bf16, 8 elems/thread. grid*256*8 must equal element count.
__global__ __launch_bounds__(256) void convert_bf16_kernel(
        const float* __restrict__ in, u16* __restrict__ out) {
    int i = blockIdx.x * 256 + threadIdx.x;
    const float4* p = (const float4*)in;
    float4 a = p[i * 2], b = p[i * 2 + 1];
    ((u16x8*)out)[i] = u16x8{f2bf(a.x), f2bf(a.y), f2bf(a.z), f2bf(a.w),
                             f2bf(b.x), f2bf(b.y), f2bf(b.z), f2bf(b.w)};
}

// ---------------------------------------------------------------------------
// past_k/past_v [B,H,P,D] f32 -> k/v f32 cache [B,H,L,D] (l<P) + kb bf16 cache.
__global__ __launch_bounds__(256) void copy_past_kernel(
        const float4* __restrict__ pk, const float4* __restrict__ pv,
        float4* __restrict__ kdst, float4* __restrict__ vdst,
        u16x4* __restrict__ kb) {
    int i = blockIdx.x * 256 + threadIdx.x;   // float4 idx; total 1048576
    int bh = i >> 15;                          // / (P*D/4 = 32768)
    int rest = i & 32767;
    size_t dst = (size_t)bh * (L_ * D_ / 4) + rest;
    float4 k4 = pk[i], v4 = pv[i];
    kdst[dst] = k4;
    vdst[dst] = v4;
    kb[dst] = u16x4{f2bf(k4.x), f2bf(k4.y), f2bf(k4.z), f2bf(k4.w)};
}

// ---------------------------------------------------------------------------
// past_v [B,H,P,D] f32 -> vbT [B,H,D,L] bf16 (cols l<P). 64x64 LDS transpose.
__global__ __launch_bounds__(256) void vT_past_kernel(
        const float* __restrict__ pv, u16* __restrict__ vbT) {
    __shared__ float s[64][65];
    const int tid = threadIdx.x;
    const int bh = blockIdx.x >> 5;           // 32 tiles per (b,h)
    const int tile = blockIdx.x & 31;
    const int k0 = (tile >> 1) * 64;          // 16 k-tiles
    const int d0 = (tile & 1) * 64;           // 2 d-tiles
    const float* src = pv + ((size_t)bh * P_ + k0) * D_ + d0;
    {
        int r = tid >> 2, c0 = (tid & 3) * 16;
#pragma unroll
        for (int u = 0; u < 4; ++u) {
            float4 f = *(const float4*)(src + (size_t)r * D_ + c0 + u * 4);
            s[r][c0 + u * 4 + 0] = f.x; s[r][c0 + u * 4 + 1] = f.y;
            s[r][c0 + u * 4 + 2] = f.z; s[r][c0 + u * 4 + 3] = f.w;
        }
    }
    __syncthreads();
    int d = tid >> 2, ck = (tid & 3) * 16;
    u16* dst = vbT + ((size_t)bh * D_ + d0 + d) * L_ + k0 + ck;
    u16x8 o0, o1;
#pragma unroll
    for (int j = 0; j < 8; ++j) o0[j] = f2bf(s[ck + j][d]);
#pragma unroll
    for (int j = 0; j < 8; ++j) o1[j] = f2bf(s[ck + 8 + j][d]);
    *(u16x8*)dst = o0;
    *(u16x8*)(dst + 8) = o1;
}

// ---------------------------------------------------------------------------
// m97-style NT GEMM: C[m,n] = sum_k A[m,k]*B[n,k], A/B bf16 [.,2048].
// 128x128 tile, 256 threads (4 waves, 2x2), BK=32, global_load_lds width 16.
// MODE 0: bf16 out[m*C+n].       MODE 2: f32 out[m*C+n] + bias.
// MODE 1: f32 KV-cache scatter + bf16 kb cache (both [B,H,L,D], l=P+t).
// MODE 3: f32 KV-cache scatter + bf16 vbT cache [B,H,D,L] (l=P+t).
template <int MODE>
__global__ __launch_bounds__(256) void gemm128(
        const u16* __restrict__ A, const u16* __restrict__ Bw,
        float* __restrict__ outf, u16* __restrict__ outb,
        const float* __restrict__ bias) {
    __shared__ u16 As[128 * 32];
    __shared__ u16 Bs[128 * 32];
    const int tid  = threadIdx.x;
    const int wave = tid >> 6;
    const int lane = tid & 63;
    const int m0 = blockIdx.y * 128;
    const int n0 = blockIdx.x * 128;

    f32x4 acc[4][4];
#pragma unroll
    for (int i = 0; i < 4; ++i)
#pragma unroll
        for (int j = 0; j < 4; ++j) acc[i][j] = f32x4{0.f, 0.f, 0.f, 0.f};

    // Staging: 8 x 1KB issues per operand; wave w does issues {2w, 2w+1}.
    // Issue q covers rows q*16..q*16+15 (32 bf16 each); lane -> row q*16+(lane>>2),
    // cols (lane&3)*8..+7  == LDS offset lane*16B (matches HW lane scatter).
    const int srow = lane >> 2;
    const int scol = (lane & 3) * 8;
    const int q0 = wave * 2, q1 = wave * 2 + 1;
    const u16* A0 = A  + (size_t)(m0 + q0 * 16 + srow) * C_ + scol;
    const u16* A1 = A  + (size_t)(m0 + q1 * 16 + srow) * C_ + scol;
    const u16* B0 = Bw + (size_t)(n0 + q0 * 16 + srow) * C_ + scol;
    const u16* B1 = Bw + (size_t)(n0 + q1 * 16 + srow) * C_ + scol;

    const int frow = lane & 15;
    const int fko  = (lane >> 4) * 8;
    const int wr = (wave >> 1) * 64;   // wave's 64x64 quadrant
    const int wc = (wave & 1) * 64;

    for (int kt = 0; kt < C_; kt += 32) {
        __syncthreads();               // prior LDS reads done
        gload_lds16(A0 + kt, &As[q0 * 512]);
        gload_lds16(A1 + kt, &As[q1 * 512]);
        gload_lds16(B0 + kt, &Bs[q0 * 512]);
        gload_lds16(B1 + kt, &Bs[q1 * 512]);
        __syncthreads();               // vmcnt(0) drained by compiler before barrier
        short8 af[4], bf[4];
#pragma unroll
        for (int i = 0; i < 4; ++i) {
            af[i] = *(const short8*)&As[(wr + i * 16 + frow) * 32 + fko];
            bf[i] = *(const short8*)&Bs[(wc + i * 16 + frow) * 32 + fko];
        }
#pragma unroll
        for (int mi = 0; mi < 4; ++mi)
#pragma unroll
            for (int ni = 0; ni < 4; ++ni)
                acc[mi][ni] = __builtin_amdgcn_mfma_f32_16x16x32_bf16(
                    af[mi], bf[ni], acc[mi][ni], 0, 0, 0);
    }

    // C/D layout: col = lane&15, row = (lane>>4)*4 + reg  [m89/m91]
    const int ccol = lane & 15;
    const int crb  = (lane >> 4) * 4;
#pragma unroll
    for (int mi = 0; mi < 4; ++mi) {
#pragma unroll
        for (int ni = 0; ni < 4; ++ni) {
            const int gc  = n0 + wc + ni * 16 + ccol;
            const int grb = m0 + wr + mi * 16 + crb;
            if (MODE == 0) {
#pragma unroll
                for (int r = 0; r < 4; ++r)
                    outb[(size_t)(grb + r) * C_ + gc] = f2bf(acc[mi][ni][r]);
            } else if (MODE == 2) {
                const float ba = bias[gc];
#pragma unroll
                for (int r = 0; r < 4; ++r)
                    outf[(size_t)(grb + r) * C_ + gc] = acc[mi][ni][r] + ba;
            } else {
                const int b = grb >> 10, tb = grb & 1023;   // grb = b*T + t
                const int h = gc >> 7,  d  = gc & 127;      // gc  = h*D + d
                const size_t fb = (((size_t)(b * H_ + h)) * L_ + P_ + tb) * D_ + d;
#pragma unroll
                for (int r = 0; r < 4; ++r) outf[fb + (size_t)r * D_] = acc[mi][ni][r];
                if (MODE == 1) {
#pragma unroll
                    for (int r = 0; r < 4; ++r)
                        outb[fb + (size_t)r * D_] = f2bf(acc[mi][ni][r]);
                } else {   // MODE 3: vbT[b,h,d, P+t..], 4 consecutive t -> u16x4
                    const size_t tb2 = (((size_t)(b * H_ + h)) * D_ + d) * L_ + P_ + tb;
                    *(u16x4*)&outb[tb2] = u16x4{
                        f2bf(acc[mi][ni][0]), f2bf(acc[mi][ni][1]),
                        f2bf(acc[mi][ni][2]), f2bf(acc[mi][ni][3])};
                }
            }
        }
    }
}

// ---------------------------------------------------------------------------
// MFMA flash attention. One block = (b, h, 64 q-rows). K/V chunks of 64 keys.
// Q bf16 [B,T,C]; Kb bf16 [B,H,L,D]; VT bf16 [B,H,D,L]; O bf16 [B,T,C].
// All tiles staged via global_load_lds with pre-swizzled SOURCE (m173):
// LDS 16B-block index ^= (row&7)  ->  conflict-free ds_read_b128 on reads.
#define NEG_BIG -30000.f
__global__ __launch_bounds__(256) void attn_kernel(
        const u16* __restrict__ Q, const u16* __restrict__ Kb,
        const u16* __restrict__ VT, u16* __restrict__ O) {
    __shared__ u16 Qs[64 * 128];   // [qrow][d]   swizzled
    __shared__ u16 Ks[64 * 128];   // [key][d]    swizzled
    __shared__ u16 Vs[128 * 64];   // [d][key]    swizzled (V^T)
    __shared__ u16 Ps[64][72];     // P tile

    const int tid  = threadIdx.x;
    const int wave = tid >> 6;
    const int lane = tid & 63;
    const int qt = blockIdx.x & 15;
    const int h  = (blockIdx.x >> 4) & 15;
    const int b  = blockIdx.x >> 8;
    const int t0 = qt * 64;

    const u16* Kbase = Kb + (size_t)(b * H_ + h) * L_ * D_;
    const u16* Vbase = VT + (size_t)(b * H_ + h) * D_ * L_;

    // Stage Q tile (64x128, 16KB = 16 x 1KB issues, 4 per wave), swizzled source.
#pragma unroll
    for (int i = 0; i < 4; ++i) {
        int g   = (wave * 4 + i) * 64 + lane;   // 16B-block id 0..1023
        int row = g >> 4, blk = g & 15;
        int sb  = (blk & 8) | ((blk ^ row) & 7);
        gload_lds16(Q + ((size_t)(b * T_ + t0 + row)) * C_ + h * D_ + sb * 8,
                    &Qs[(wave * 4 + i) * 512]);
    }

    const int frow = lane & 15;
    const int quad = lane >> 4;
    const int fko  = quad * 8;
    const int swz  = (frow & 7) << 3;   // u16-index XOR (flips 16B-block low bits)

    f32x4 o_acc[8];
#pragma unroll
    for (int n = 0; n < 8; ++n) o_acc[n] = f32x4{0.f, 0.f, 0.f, 0.f};
    float m_i[4] = {NEG_BIG, NEG_BIG, NEG_BIG, NEG_BIG};
    float l_i[4] = {0.f, 0.f, 0.f, 0.f};
    const float scale = 0.08838834764831845f;   // 1/sqrt(128)

    const int nch = (P_ + t0 + 64) >> 6;

    for (int ch = 0; ch < nch; ++ch) {
        const int j0 = ch * 64;
        __syncthreads();   // prior iter's LDS consumers done (covers Q staging)
        // Stage K (row-major) and V^T chunk, both swizzled-source, async.
#pragma unroll
        for (int i = 0; i < 4; ++i) {
            int g = (wave * 4 + i) * 64 + lane;
            {   // K: row = key (64 rows x 128 d), 16 blocks/row
                int row = g >> 4, blk = g & 15;
                int sb  = (blk & 8) | ((blk ^ row) & 7);
                gload_lds16(Kbase + (size_t)(j0 + row) * D_ + sb * 8,
                            &Ks[(wave * 4 + i) * 512]);
            }
            {   // V^T: row = d (128 rows x 64 keys), 8 blocks/row
                int d  = g >> 3, cb = g & 7;
                int sb = (cb ^ d) & 7;
                gload_lds16(Vbase + (size_t)d * L_ + j0 + sb * 8,
                            &Vs[(wave * 4 + i) * 512]);
            }
        }
        __syncthreads();

        // S = Q(wave's 16 rows) @ K^T  -> 4 col-tiles of 16 keys
        f32x4 st[4];
#pragma unroll
        for (int j = 0; j < 4; ++j) st[j] = f32x4{0.f, 0.f, 0.f, 0.f};
#pragma unroll
        for (int kt = 0; kt < 4; ++kt) {
            short8 a = *(const short8*)&Qs[(wave * 16 + frow) * 128 +
                                           ((kt * 32 + fko) ^ swz)];
#pragma unroll
            for (int j = 0; j < 4; ++j) {
                short8 kf = *(const short8*)&Ks[(j * 16 + frow) * 128 +
                                                ((kt * 32 + fko) ^ swz)];
                st[j] = __builtin_amdgcn_mfma_f32_16x16x32_bf16(a, kf, st[j], 0, 0, 0);
            }
        }

        // Online softmax. Lane holds rows quad*4+r, col frow (+16j).
#pragma unroll
        for (int r = 0; r < 4; ++r) {
            const int t   = t0 + wave * 16 + quad * 4 + r;
            const int lim = P_ + t;
            float sv[4];
            float mx = NEG_BIG;
#pragma unroll
            for (int j = 0; j < 4; ++j) {
                int jg = j0 + j * 16 + frow;
                float s = st[j][r] * scale;
                s = (jg <= lim) ? s : NEG_BIG;
                sv[j] = s;
                mx = fmaxf(mx, s);
            }
#pragma unroll
            for (int sft = 1; sft <= 8; sft <<= 1)
                mx = fmaxf(mx, __shfl_xor(mx, sft, 64));
            float m_new = fmaxf(m_i[r], mx);
            float alpha = __expf(fminf(m_i[r] - m_new, 0.f));
            float rs = 0.f;
#pragma unroll
            for (int j = 0; j < 4; ++j) {
                float p = __expf(fminf(sv[j] - m_new, 0.f));
                p = (sv[j] <= NEG_BIG) ? 0.f : p;
                sv[j] = p;
                rs += p;
            }
#pragma unroll
            for (int sft = 1; sft <= 8; sft <<= 1)
                rs += __shfl_xor(rs, sft, 64);
            l_i[r] = l_i[r] * alpha + rs;
            m_i[r] = m_new;
#pragma unroll
            for (int n = 0; n < 8; ++n) o_acc[n][r] *= alpha;
#pragma unroll
            for (int j = 0; j < 4; ++j)
                Ps[wave * 16 + quad * 4 + r][j * 16 + frow] = f2bf(sv[j]);
        }
        __syncthreads();   // Ps stores visible

        // PV: O(16x128) += P(16x64) @ V(64x128), B-operand from swizzled V^T.
#pragma unroll
        for (int kt2 = 0; kt2 < 2; ++kt2) {
            short8 a = *(const short8*)&Ps[wave * 16 + frow][kt2 * 32 + fko];
#pragma unroll
            for (int n = 0; n < 8; ++n) {
                short8 vf = *(const short8*)&Vs[(n * 16 + frow) * 64 +
                                                ((kt2 * 32 + fko) ^ swz)];
                o_acc[n] = __builtin_amdgcn_mfma_f32_16x16x32_bf16(a, vf, o_acc[n], 0, 0, 0);
            }
        }
    }

    // Epilogue: O /= l, store bf16 [B,T,C]
#pragma unroll
    for (int r = 0; r < 4; ++r) {
        float rl = 1.f / fmaxf(l_i[r], 1e-30f);
        int t = t0 + wave * 16 + quad * 4 + r;
#pragma unroll
        for (int n = 0; n < 8; ++n) {
            float v = o_acc[n][r] * rl;
            O[((size_t)(b * T_ + t)) * C_ + h * D_ + n * 16 + frow] = f2bf(v);
        }
    }
}

// ---------------------------------------------------------------------------
extern "C" void kernel_launch(void* const* d_in, const int* in_sizes, int n_in,
                              void* d_out, int out_size, void* d_ws, size_t ws_size,
                              hipStream_t stream) {
    const float* x      = (const float*)d_in[0];
    const float* past_k = (const float*)d_in[1];
    const float* past_v = (const float*)d_in[2];
    const float* Wk     = (const float*)d_in[3];
    const float* Wq     = (const float*)d_in[4];
    const float* Wv     = (const float*)d_in[5];
    const float* Wp     = (const float*)d_in[6];
    const float* bp     = (const float*)d_in[7];

    float* out  = (float*)d_out;             // [B,T,C]    16 MB
    float* kout = out + 4194304;             // [B,H,L,D]  32 MB
    float* vout = kout + 8388608;            // [B,H,L,D]  32 MB

    // d_out scratch (dead until final GEMM writes out): Qst + xb.
    u16* Qst = (u16*)d_out;                          //  8 MB bf16 Q
    u16* xb  = (u16*)((char*)d_out + (8u << 20));    //  8 MB bf16 x
    // d_ws layout (48 MB total):
    u16* Ost = (u16*)d_ws;                           //  8 MB bf16 attn out
    u16* kb  = (u16*)((char*)d_ws + (8u  << 20));    // 16 MB bf16 K cache [B,H,L,D]
    u16* vbT = (u16*)((char*)d_ws + (24u << 20));    // 16 MB bf16 V^T cache [B,H,D,L]
    u16* Wb  = (u16*)((char*)d_ws + (40u << 20));    //  8 MB bf16 weight (reused 4x)

    copy_past_kernel<<<4096, 256, 0, stream>>>(
        (const float4*)past_k, (const float4*)past_v,
        (float4*)kout, (float4*)vout, (u16x4*)kb);
    vT_past_kernel<<<1024, 256, 0, stream>>>(past_v, vbT);
    convert_bf16_kernel<<<2048, 256, 0, stream>>>(x, xb);

    dim3 g(16, 16);
    convert_bf16_kernel<<<2048, 256, 0, stream>>>(Wk, Wb);
    gemm128<1><<<g, 256, 0, stream>>>(xb, Wb, kout, kb, nullptr);
    convert_bf16_kernel<<<2048, 256, 0, stream>>>(Wv, Wb);
    gemm128<3><<<g, 256, 0, stream>>>(xb, Wb, vout, vbT, nullptr);
    convert_bf16_kernel<<<2048, 256, 0, stream>>>(Wq, Wb);
    gemm128<0><<<g, 256, 0, stream>>>(xb, Wb, nullptr, Qst, nullptr);

    attn_kernel<<<512, 256, 0, stream>>>(Qst, kb, vbT, Ost);

    convert_bf16_kernel<<<2048, 256, 0, stream>>>(Wp, Wb);
    gemm128<2><<<g, 256, 0, stream>>>(Ost, Wb, out, nullptr, bp);
}

// Round 3
// 443.328 us; speedup vs baseline: 1.6604x; 1.0749x over previous
//
#include <hip/hip_runtime.h>
#include <stdint.h>

#define B_ 2
#define T_ 1024
#define C_ 2048
#define H_ 16
#define D_ 128
#define P_ 1024
#define L_ 2048   // P + T
#define M_ 2048   // B*T

typedef unsigned short u16;
typedef __attribute__((ext_vector_type(8))) short short8;   // MFMA A/B frag (8 bf16)
typedef __attribute__((ext_vector_type(4))) float f32x4;    // MFMA C/D frag
typedef __attribute__((ext_vector_type(8))) u16 u16x8;      // 16B vector
typedef __attribute__((ext_vector_type(4))) u16 u16x4;      // 8B vector

__device__ __forceinline__ u16 f2bf(float x) {
    union { float f; uint32_t u; } c; c.f = x;
    uint32_t u = c.u;
    return (u16)((u + 0x7fffu + ((u >> 16) & 1u)) >> 16);   // RNE
}

// Async global->LDS, 16B per lane. LDS dest = uniform base + lane*16 (HW rule).
__device__ __forceinline__ void gload_lds16(const void* g, void* l) {
    typedef __attribute__((address_space(1))) const void gvoid;
    typedef __attribute__((address_space(3))) void lvoid;
    __builtin_amdgcn_global_load_lds((gvoid*)g, (lvoid*)l, 16, 0, 0);
}

// ---------------------------------------------------------------------------
// Fused f32->bf16 for x, Wk, Wv, Wq (4 x 4M elems). Region by blockIdx>>11.
__global__ __launch_bounds__(256) void convert4_kernel(
        const float* __restrict__ x,  const float* __restrict__ wk,
        const float* __restrict__ wv, const float* __restrict__ wq,
        u16* __restrict__ xb, u16* __restrict__ obK,
        u16* __restrict__ obV, u16* __restrict__ obQ) {
    const int bid = blockIdx.x;
    const int r = bid >> 11;
    const int i = (bid & 2047) * 256 + threadIdx.x;
    const float* src = (r == 0) ? x : (r == 1) ? wk : (r == 2) ? wv : wq;
    u16* dst = (r == 0) ? xb : (r == 1) ? obK : (r == 2) ? obV : obQ;
    float4 a = ((const float4*)src)[i * 2], b = ((const float4*)src)[i * 2 + 1];
    ((u16x8*)dst)[i] = u16x8{f2bf(a.x), f2bf(a.y), f2bf(a.z), f2bf(a.w),
                             f2bf(b.x), f2bf(b.y), f2bf(b.z), f2bf(b.w)};
}

// Single-source convert (Wp, after QKV GEMM frees its slot).
__global__ __launch_bounds__(256) void convert_bf16_kernel(
        const float* __restrict__ in, u16* __restrict__ out) {
    int i = blockIdx.x * 256 + threadIdx.x;
    const float4* p = (const float4*)in;
    float4 a = p[i * 2], b = p[i * 2 + 1];
    ((u16x8*)out)[i] = u16x8{f2bf(a.x), f2bf(a.y), f2bf(a.z), f2bf(a.w),
                             f2bf(b.x), f2bf(b.y), f2bf(b.z), f2bf(b.w)};
}

// ---------------------------------------------------------------------------
// past_k/past_v [B,H,P,D] f32 -> k/v f32 cache [B,H,L,D] (l<P) + kb bf16 cache.
__global__ __launch_bounds__(256) void copy_past_kernel(
        const float4* __restrict__ pk, const float4* __restrict__ pv,
        float4* __restrict__ kdst, float4* __restrict__ vdst,
        u16x4* __restrict__ kb) {
    int i = blockIdx.x * 256 + threadIdx.x;   // float4 idx; total 1048576
    int bh = i >> 15;                          // / (P*D/4 = 32768)
    int rest = i & 32767;
    size_t dst = (size_t)bh * (L_ * D_ / 4) + rest;
    float4 k4 = pk[i], v4 = pv[i];
    kdst[dst] = k4;
    vdst[dst] = v4;
    kb[dst] = u16x4{f2bf(k4.x), f2bf(k4.y), f2bf(k4.z), f2bf(k4.w)};
}

// ---------------------------------------------------------------------------
// past_v [B,H,P,D] f32 -> vbT [B,H,D,L] bf16 (cols l<P). 64x64 LDS transpose.
__global__ __launch_bounds__(256) void vT_past_kernel(
        const float* __restrict__ pv, u16* __restrict__ vbT) {
    __shared__ float s[64][65];
    const int tid = threadIdx.x;
    const int bh = blockIdx.x >> 5;           // 32 tiles per (b,h)
    const int tile = blockIdx.x & 31;
    const int k0 = (tile >> 1) * 64;          // 16 k-tiles
    const int d0 = (tile & 1) * 64;           // 2 d-tiles
    const float* src = pv + ((size_t)bh * P_ + k0) * D_ + d0;
    {
        int r = tid >> 2, c0 = (tid & 3) * 16;
#pragma unroll
        for (int u = 0; u < 4; ++u) {
            float4 f = *(const float4*)(src + (size_t)r * D_ + c0 + u * 4);
            s[r][c0 + u * 4 + 0] = f.x; s[r][c0 + u * 4 + 1] = f.y;
            s[r][c0 + u * 4 + 2] = f.z; s[r][c0 + u * 4 + 3] = f.w;
        }
    }
    __syncthreads();
    int d = tid >> 2, ck = (tid & 3) * 16;
    u16* dst = vbT + ((size_t)bh * D_ + d0 + d) * L_ + k0 + ck;
    u16x8 o0, o1;
#pragma unroll
    for (int j = 0; j < 8; ++j) o0[j] = f2bf(s[ck + j][d]);
#pragma unroll
    for (int j = 0; j < 8; ++j) o1[j] = f2bf(s[ck + 8 + j][d]);
    *(u16x8*)dst = o0;
    *(u16x8*)(dst + 8) = o1;
}

// ---------------------------------------------------------------------------
// Fused QKV NT GEMM: C[m,n] = sum_k xb[m,k]*W[n,k]. N-space = [K | V | Q]
// regions of 2048 cols each; grid.x = 32 (K,V only) or 48 (K,V,Q).
// 128x128 tile, 256 threads (4 waves, 2x2), BK=32, global_load_lds width 16.
__global__ __launch_bounds__(256) void gemm_qkv(
        const u16* __restrict__ A,
        const u16* __restrict__ wbK, const u16* __restrict__ wbV,
        const u16* __restrict__ wbQ,
        float* __restrict__ kout, float* __restrict__ vout,
        u16* __restrict__ kb, u16* __restrict__ vbT, u16* __restrict__ Qst) {
    __shared__ u16 As[128 * 32];
    __shared__ u16 Bs[128 * 32];
    const int tid  = threadIdx.x;
    const int wave = tid >> 6;
    const int lane = tid & 63;
    const int m0   = blockIdx.y * 128;
    const int n0g  = blockIdx.x * 128;
    const int region = n0g >> 11;            // 0=K 1=V 2=Q
    const int n0   = n0g & 2047;
    const u16* Bw = (region == 0) ? wbK : (region == 1) ? wbV : wbQ;

    f32x4 acc[4][4];
#pragma unroll
    for (int i = 0; i < 4; ++i)
#pragma unroll
        for (int j = 0; j < 4; ++j) acc[i][j] = f32x4{0.f, 0.f, 0.f, 0.f};

    const int srow = lane >> 2;
    const int scol = (lane & 3) * 8;
    const int q0 = wave * 2, q1 = wave * 2 + 1;
    const u16* A0 = A  + (size_t)(m0 + q0 * 16 + srow) * C_ + scol;
    const u16* A1 = A  + (size_t)(m0 + q1 * 16 + srow) * C_ + scol;
    const u16* B0 = Bw + (size_t)(n0 + q0 * 16 + srow) * C_ + scol;
    const u16* B1 = Bw + (size_t)(n0 + q1 * 16 + srow) * C_ + scol;

    const int frow = lane & 15;
    const int fko  = (lane >> 4) * 8;
    const int wr = (wave >> 1) * 64;
    const int wc = (wave & 1) * 64;

    for (int kt = 0; kt < C_; kt += 32) {
        __syncthreads();
        gload_lds16(A0 + kt, &As[q0 * 512]);
        gload_lds16(A1 + kt, &As[q1 * 512]);
        gload_lds16(B0 + kt, &Bs[q0 * 512]);
        gload_lds16(B1 + kt, &Bs[q1 * 512]);
        __syncthreads();
        short8 af[4], bf[4];
#pragma unroll
        for (int i = 0; i < 4; ++i) {
            af[i] = *(const short8*)&As[(wr + i * 16 + frow) * 32 + fko];
            bf[i] = *(const short8*)&Bs[(wc + i * 16 + frow) * 32 + fko];
        }
#pragma unroll
        for (int mi = 0; mi < 4; ++mi)
#pragma unroll
            for (int ni = 0; ni < 4; ++ni)
                acc[mi][ni] = __builtin_amdgcn_mfma_f32_16x16x32_bf16(
                    af[mi], bf[ni], acc[mi][ni], 0, 0, 0);
    }

    const int ccol = lane & 15;
    const int crb  = (lane >> 4) * 4;
#pragma unroll
    for (int mi = 0; mi < 4; ++mi) {
#pragma unroll
        for (int ni = 0; ni < 4; ++ni) {
            const int gc  = n0 + wc + ni * 16 + ccol;
            const int grb = m0 + wr + mi * 16 + crb;
            if (region == 2) {
#pragma unroll
                for (int r = 0; r < 4; ++r)
                    Qst[(size_t)(grb + r) * C_ + gc] = f2bf(acc[mi][ni][r]);
            } else {
                const int b = grb >> 10, tb = grb & 1023;
                const int h = gc >> 7,  d  = gc & 127;
                const size_t fb = (((size_t)(b * H_ + h)) * L_ + P_ + tb) * D_ + d;
                if (region == 0) {
#pragma unroll
                    for (int r = 0; r < 4; ++r) {
                        kout[fb + (size_t)r * D_] = acc[mi][ni][r];
                        kb[fb + (size_t)r * D_]   = f2bf(acc[mi][ni][r]);
                    }
                } else {
#pragma unroll
                    for (int r = 0; r < 4; ++r) vout[fb + (size_t)r * D_] = acc[mi][ni][r];
                    const size_t tb2 = (((size_t)(b * H_ + h)) * D_ + d) * L_ + P_ + tb;
                    *(u16x4*)&vbT[tb2] = u16x4{
                        f2bf(acc[mi][ni][0]), f2bf(acc[mi][ni][1]),
                        f2bf(acc[mi][ni][2]), f2bf(acc[mi][ni][3])};
                }
            }
        }
    }
}

// ---------------------------------------------------------------------------
// Plain NT GEMM (m97 structure). MODE 0: bf16 out. MODE 2: f32 out + bias.
template <int MODE>
__global__ __launch_bounds__(256) void gemm128(
        const u16* __restrict__ A, const u16* __restrict__ Bw,
        float* __restrict__ outf, u16* __restrict__ outb,
        const float* __restrict__ bias) {
    __shared__ u16 As[128 * 32];
    __shared__ u16 Bs[128 * 32];
    const int tid  = threadIdx.x;
    const int wave = tid >> 6;
    const int lane = tid & 63;
    const int m0 = blockIdx.y * 128;
    const int n0 = blockIdx.x * 128;

    f32x4 acc[4][4];
#pragma unroll
    for (int i = 0; i < 4; ++i)
#pragma unroll
        for (int j = 0; j < 4; ++j) acc[i][j] = f32x4{0.f, 0.f, 0.f, 0.f};

    const int srow = lane >> 2;
    const int scol = (lane & 3) * 8;
    const int q0 = wave * 2, q1 = wave * 2 + 1;
    const u16* A0 = A  + (size_t)(m0 + q0 * 16 + srow) * C_ + scol;
    const u16* A1 = A  + (size_t)(m0 + q1 * 16 + srow) * C_ + scol;
    const u16* B0 = Bw + (size_t)(n0 + q0 * 16 + srow) * C_ + scol;
    const u16* B1 = Bw + (size_t)(n0 + q1 * 16 + srow) * C_ + scol;

    const int frow = lane & 15;
    const int fko  = (lane >> 4) * 8;
    const int wr = (wave >> 1) * 64;
    const int wc = (wave & 1) * 64;

    for (int kt = 0; kt < C_; kt += 32) {
        __syncthreads();
        gload_lds16(A0 + kt, &As[q0 * 512]);
        gload_lds16(A1 + kt, &As[q1 * 512]);
        gload_lds16(B0 + kt, &Bs[q0 * 512]);
        gload_lds16(B1 + kt, &Bs[q1 * 512]);
        __syncthreads();
        short8 af[4], bf[4];
#pragma unroll
        for (int i = 0; i < 4; ++i) {
            af[i] = *(const short8*)&As[(wr + i * 16 + frow) * 32 + fko];
            bf[i] = *(const short8*)&Bs[(wc + i * 16 + frow) * 32 + fko];
        }
#pragma unroll
        for (int mi = 0; mi < 4; ++mi)
#pragma unroll
            for (int ni = 0; ni < 4; ++ni)
                acc[mi][ni] = __builtin_amdgcn_mfma_f32_16x16x32_bf16(
                    af[mi], bf[ni], acc[mi][ni], 0, 0, 0);
    }

    const int ccol = lane & 15;
    const int crb  = (lane >> 4) * 4;
#pragma unroll
    for (int mi = 0; mi < 4; ++mi) {
#pragma unroll
        for (int ni = 0; ni < 4; ++ni) {
            const int gc  = n0 + wc + ni * 16 + ccol;
            const int grb = m0 + wr + mi * 16 + crb;
            if (MODE == 0) {
#pragma unroll
                for (int r = 0; r < 4; ++r)
                    outb[(size_t)(grb + r) * C_ + gc] = f2bf(acc[mi][ni][r]);
            } else {
                const float ba = bias[gc];
#pragma unroll
                for (int r = 0; r < 4; ++r)
                    outf[(size_t)(grb + r) * C_ + gc] = acc[mi][ni][r] + ba;
            }
        }
    }
}

// ---------------------------------------------------------------------------
// MFMA flash attention. One block = (b, h, 64 q-rows). K/V chunks of 64 keys.
// Q bf16 [B,T,C]; Kb bf16 [B,H,L,D]; VT bf16 [B,H,D,L]; O bf16 [B,T,C].
// Swizzled-source global_load_lds staging (conflict-free ds_read_b128).
#define NEG_BIG -30000.f
__global__ __launch_bounds__(256) void attn_kernel(
        const u16* __restrict__ Q, const u16* __restrict__ Kb,
        const u16* __restrict__ VT, u16* __restrict__ O) {
    __shared__ u16 Qs[64 * 128];   // [qrow][d]   swizzled
    __shared__ u16 Ks[64 * 128];   // [key][d]    swizzled
    __shared__ u16 Vs[128 * 64];   // [d][key]    swizzled (V^T)
    __shared__ u16 Ps[64][72];     // P tile

    const int tid  = threadIdx.x;
    const int wave = tid >> 6;
    const int lane = tid & 63;
    int       qt = blockIdx.x & 15;
    const int h  = (blockIdx.x >> 4) & 15;
    const int b  = blockIdx.x >> 8;
    // Load-balance: CU gets blocks c and c+256 (same qt, different b).
    // Flip qt for b=1 so each CU's pair sums to a uniform 49 chunks.
    if (b) qt = 15 - qt;
    const int t0 = qt * 64;

    const u16* Kbase = Kb + (size_t)(b * H_ + h) * L_ * D_;
    const u16* Vbase = VT + (size_t)(b * H_ + h) * D_ * L_;

    // Stage Q tile (64x128, 16 x 1KB issues, 4 per wave), swizzled source.
#pragma unroll
    for (int i = 0; i < 4; ++i) {
        int g   = (wave * 4 + i) * 64 + lane;   // 16B-block id 0..1023
        int row = g >> 4, blk = g & 15;
        int sb  = (blk & 8) | ((blk ^ row) & 7);
        gload_lds16(Q + ((size_t)(b * T_ + t0 + row)) * C_ + h * D_ + sb * 8,
                    &Qs[(wave * 4 + i) * 512]);
    }

    const int frow = lane & 15;
    const int quad = lane >> 4;
    const int fko  = quad * 8;
    const int swz  = (frow & 7) << 3;

    f32x4 o_acc[8];
#pragma unroll
    for (int n = 0; n < 8; ++n) o_acc[n] = f32x4{0.f, 0.f, 0.f, 0.f};
    float m_i[4] = {NEG_BIG, NEG_BIG, NEG_BIG, NEG_BIG};
    float l_i[4] = {0.f, 0.f, 0.f, 0.f};
    const float scale = 0.08838834764831845f;   // 1/sqrt(128)

    const int nch = (P_ + t0 + 64) >> 6;
    const int wave_lim = P_ + t0 + wave * 16 + 15;   // max key this wave attends

    for (int ch = 0; ch < nch; ++ch) {
        const int j0 = ch * 64;
        __syncthreads();   // prior iter's LDS consumers done (covers Q staging)
#pragma unroll
        for (int i = 0; i < 4; ++i) {
            int g = (wave * 4 + i) * 64 + lane;
            {   // K: 64 rows x 128 d, 16 blocks/row
                int row = g >> 4, blk = g & 15;
                int sb  = (blk & 8) | ((blk ^ row) & 7);
                gload_lds16(Kbase + (size_t)(j0 + row) * D_ + sb * 8,
                            &Ks[(wave * 4 + i) * 512]);
            }
            {   // V^T: 128 rows x 64 keys, 8 blocks/row
                int d  = g >> 3, cb = g & 7;
                int sb = (cb ^ d) & 7;
                gload_lds16(Vbase + (size_t)d * L_ + j0 + sb * 8,
                            &Vs[(wave * 4 + i) * 512]);
            }
        }
        __syncthreads();

        const bool active = (j0 <= wave_lim);   // any unmasked key for this wave?

        if (active) {
            // S = Q(wave's 16 rows) @ K^T  -> 4 col-tiles of 16 keys
            f32x4 st[4];
#pragma unroll
            for (int j = 0; j < 4; ++j) st[j] = f32x4{0.f, 0.f, 0.f, 0.f};
            __builtin_amdgcn_s_setprio(1);
#pragma unroll
            for (int kt = 0; kt < 4; ++kt) {
                short8 a = *(const short8*)&Qs[(wave * 16 + frow) * 128 +
                                               ((kt * 32 + fko) ^ swz)];
#pragma unroll
                for (int j = 0; j < 4; ++j) {
                    short8 kf = *(const short8*)&Ks[(j * 16 + frow) * 128 +
                                                    ((kt * 32 + fko) ^ swz)];
                    st[j] = __builtin_amdgcn_mfma_f32_16x16x32_bf16(a, kf, st[j], 0, 0, 0);
                }
            }
            __builtin_amdgcn_s_setprio(0);

            // Online softmax with defer-max (skip rescale when max grows < 8).
#pragma unroll
            for (int r = 0; r < 4; ++r) {
                const int t   = t0 + wave * 16 + quad * 4 + r;
                const int lim = P_ + t;
                float sv[4];
                float mx = NEG_BIG;
#pragma unroll
                for (int j = 0; j < 4; ++j) {
                    int jg = j0 + j * 16 + frow;
                    float s = st[j][r] * scale;
                    s = (jg <= lim) ? s : NEG_BIG;
                    sv[j] = s;
                    mx = fmaxf(mx, s);
                }
#pragma unroll
                for (int sft = 1; sft <= 8; sft <<= 1)
                    mx = fmaxf(mx, __shfl_xor(mx, sft, 64));
                const bool defer = (mx <= m_i[r] + 8.f);
                const float m_new = defer ? m_i[r] : mx;
                float rs = 0.f;
#pragma unroll
                for (int j = 0; j < 4; ++j) {
                    float p = (sv[j] <= NEG_BIG) ? 0.f : __expf(sv[j] - m_new);
                    sv[j] = p;
                    rs += p;
                }
#pragma unroll
                for (int sft = 1; sft <= 8; sft <<= 1)
                    rs += __shfl_xor(rs, sft, 64);
                if (defer) {
                    l_i[r] += rs;
                } else {
                    float alpha = __expf(fminf(m_i[r] - m_new, 0.f));
                    l_i[r] = l_i[r] * alpha + rs;
                    m_i[r] = m_new;
#pragma unroll
                    for (int n = 0; n < 8; ++n) o_acc[n][r] *= alpha;
                }
#pragma unroll
                for (int j = 0; j < 4; ++j)
                    Ps[wave * 16 + quad * 4 + r][j * 16 + frow] = f2bf(sv[j]);
            }
        }
        __syncthreads();   // Ps stores visible (all waves reach this)

        if (active) {
            // PV: O(16x128) += P(16x64) @ V(64x128), B-operand from swizzled V^T.
            __builtin_amdgcn_s_setprio(1);
#pragma unroll
            for (int kt2 = 0; kt2 < 2; ++kt2) {
                short8 a = *(const short8*)&Ps[wave * 16 + frow][kt2 * 32 + fko];
#pragma unroll
                for (int n = 0; n < 8; ++n) {
                    short8 vf = *(const short8*)&Vs[(n * 16 + frow) * 64 +
                                                    ((kt2 * 32 + fko) ^ swz)];
                    o_acc[n] = __builtin_amdgcn_mfma_f32_16x16x32_bf16(a, vf, o_acc[n], 0, 0, 0);
                }
            }
            __builtin_amdgcn_s_setprio(0);
        }
    }

    // Epilogue: O /= l, store bf16 [B,T,C]
#pragma unroll
    for (int r = 0; r < 4; ++r) {
        float rl = 1.f / fmaxf(l_i[r], 1e-30f);
        int t = t0 + wave * 16 + quad * 4 + r;
#pragma unroll
        for (int n = 0; n < 8; ++n) {
            float v = o_acc[n][r] * rl;
            O[((size_t)(b * T_ + t)) * C_ + h * D_ + n * 16 + frow] = f2bf(v);
        }
    }
}

// ---------------------------------------------------------------------------
extern "C" void kernel_launch(void* const* d_in, const int* in_sizes, int n_in,
                              void* d_out, int out_size, void* d_ws, size_t ws_size,
                              hipStream_t stream) {
    const float* x      = (const float*)d_in[0];
    const float* past_k = (const float*)d_in[1];
    const float* past_v = (const float*)d_in[2];
    const float* Wk     = (const float*)d_in[3];
    const float* Wq     = (const float*)d_in[4];
    const float* Wv     = (const float*)d_in[5];
    const float* Wp     = (const float*)d_in[6];
    const float* bp     = (const float*)d_in[7];

    float* out  = (float*)d_out;             // [B,T,C]    16 MB
    float* kout = out + 4194304;             // [B,H,L,D]  32 MB
    float* vout = kout + 8388608;            // [B,H,L,D]  32 MB

    // d_out scratch (dead until final GEMM writes out):
    u16* Qst = (u16*)d_out;                          //  8 MB bf16 Q (written by Q-GEMM)
    u16* xb  = (u16*)((char*)d_out + (8u << 20));    //  8 MB bf16 x
    // d_ws (proven >= 48 MiB):
    u16* OstWq = (u16*)d_ws;                         //  8 MB: Wq bf16, then attn out
    u16* kb    = (u16*)((char*)d_ws + (8u  << 20));  // 16 MB bf16 K cache [B,H,L,D]
    u16* vbT   = (u16*)((char*)d_ws + (24u << 20));  // 16 MB bf16 V^T cache [B,H,D,L]
    u16* wbKP  = (u16*)((char*)d_ws + (40u << 20));  //  8 MB: Wk bf16, then Wp bf16
    // If workspace allows, a 5th slot lets K,V,Q fuse into one 768-block GEMM.
    const bool fused = ws_size >= (size_t)(56u << 20);
    u16* wbV = fused ? (u16*)((char*)d_ws + (48u << 20))
                     : Qst;   // fallback: Wv parked in Qst slot (dead until Q-GEMM)

    convert4_kernel<<<8192, 256, 0, stream>>>(x, Wk, Wv, Wq, xb, wbKP, wbV, OstWq);

    copy_past_kernel<<<4096, 256, 0, stream>>>(
        (const float4*)past_k, (const float4*)past_v,
        (float4*)kout, (float4*)vout, (u16x4*)kb);
    vT_past_kernel<<<1024, 256, 0, stream>>>(past_v, vbT);

    if (fused) {
        dim3 g(48, 16);   // K | V | Q regions, 768 blocks (~3/CU)
        gemm_qkv<<<g, 256, 0, stream>>>(xb, wbKP, wbV, OstWq,
                                        kout, vout, kb, vbT, Qst);
    } else {
        dim3 gkv(32, 16); // K | V regions, 512 blocks (~2/CU)
        gemm_qkv<<<gkv, 256, 0, stream>>>(xb, wbKP, wbV, OstWq,
                                          kout, vout, kb, vbT, Qst);
        dim3 gq(16, 16);
        gemm128<0><<<gq, 256, 0, stream>>>(xb, OstWq, nullptr, Qst, nullptr);
    }

    attn_kernel<<<512, 256, 0, stream>>>(Qst, kb, vbT, OstWq);

    convert_bf16_kernel<<<2048, 256, 0, stream>>>(Wp, wbKP);
    dim3 gp(16, 16);
    gemm128<2><<<gp, 256, 0, stream>>>(OstWq, wbKP, out, nullptr, bp);
}

// Round 4
// 420.506 us; speedup vs baseline: 1.7505x; 1.0543x over previous
//
#include <hip/hip_runtime.h>
#include <stdint.h>

#define B_ 2
#define T_ 1024
#define C_ 2048
#define H_ 16
#define D_ 128
#define P_ 1024
#define L_ 2048   // P + T
#define M_ 2048   // B*T

typedef unsigned short u16;
typedef __attribute__((ext_vector_type(8))) short short8;   // MFMA A/B frag (8 bf16)
typedef __attribute__((ext_vector_type(4))) float f32x4;    // MFMA C/D frag
typedef __attribute__((ext_vector_type(8))) u16 u16x8;      // 16B vector
typedef __attribute__((ext_vector_type(4))) u16 u16x4;      // 8B vector

__device__ __forceinline__ u16 f2bf(float x) {
    union { float f; uint32_t u; } c; c.f = x;
    uint32_t u = c.u;
    return (u16)((u + 0x7fffu + ((u >> 16) & 1u)) >> 16);   // RNE
}

// Async global->LDS, 16B per lane. LDS dest = uniform base + lane*16 (HW rule).
__device__ __forceinline__ void gload_lds16(const void* g, void* l) {
    typedef __attribute__((address_space(1))) const void gvoid;
    typedef __attribute__((address_space(3))) void lvoid;
    __builtin_amdgcn_global_load_lds((gvoid*)g, (lvoid*)l, 16, 0, 0);
}

// ---------------------------------------------------------------------------
// Fused prep: one launch, region-dispatched.
//   blocks [0,8192):     f32->bf16 convert of x, Wk, Wv, Wq (2048 blocks each)
//   blocks [8192,12288): past_k/past_v -> f32 caches + kb bf16 cache
//   blocks [12288,13312): past_v -> vbT [B,H,D,L] bf16 (64x64 LDS transpose)
__global__ __launch_bounds__(256) void prep_kernel(
        const float* __restrict__ x,  const float* __restrict__ wk,
        const float* __restrict__ wv, const float* __restrict__ wq,
        const float4* __restrict__ pk, const float4* __restrict__ pv,
        u16* __restrict__ xb, u16* __restrict__ obK,
        u16* __restrict__ obV, u16* __restrict__ obQ,
        float4* __restrict__ kdst, float4* __restrict__ vdst,
        u16x4* __restrict__ kb, u16* __restrict__ vbT) {
    __shared__ float s[64][65];
    const int bid = blockIdx.x;
    const int tid = threadIdx.x;
    if (bid < 8192) {
        const int r = bid >> 11;
        const int i = (bid & 2047) * 256 + tid;
        const float* src = (r == 0) ? x : (r == 1) ? wk : (r == 2) ? wv : wq;
        u16* dst = (r == 0) ? xb : (r == 1) ? obK : (r == 2) ? obV : obQ;
        float4 a = ((const float4*)src)[i * 2], b = ((const float4*)src)[i * 2 + 1];
        ((u16x8*)dst)[i] = u16x8{f2bf(a.x), f2bf(a.y), f2bf(a.z), f2bf(a.w),
                                 f2bf(b.x), f2bf(b.y), f2bf(b.z), f2bf(b.w)};
    } else if (bid < 12288) {
        const int i = (bid - 8192) * 256 + tid;    // float4 idx; total 1048576
        const int bh = i >> 15;                    // / (P*D/4 = 32768)
        const int rest = i & 32767;
        const size_t dst = (size_t)bh * (L_ * D_ / 4) + rest;
        float4 k4 = pk[i], v4 = pv[i];
        kdst[dst] = k4;
        vdst[dst] = v4;
        kb[dst] = u16x4{f2bf(k4.x), f2bf(k4.y), f2bf(k4.z), f2bf(k4.w)};
    } else {
        const int tb = bid - 12288;                // 0..1023
        const int bh = tb >> 5;                    // 32 tiles per (b,h)
        const int tile = tb & 31;
        const int k0 = (tile >> 1) * 64;           // 16 k-tiles
        const int d0 = (tile & 1) * 64;            // 2 d-tiles
        const float* src = (const float*)pv + ((size_t)bh * P_ + k0) * D_ + d0;
        {
            int r = tid >> 2, c0 = (tid & 3) * 16;
#pragma unroll
            for (int u = 0; u < 4; ++u) {
                float4 f = *(const float4*)(src + (size_t)r * D_ + c0 + u * 4);
                s[r][c0 + u * 4 + 0] = f.x; s[r][c0 + u * 4 + 1] = f.y;
                s[r][c0 + u * 4 + 2] = f.z; s[r][c0 + u * 4 + 3] = f.w;
            }
        }
        __syncthreads();
        int d = tid >> 2, ck = (tid & 3) * 16;
        u16* dst = vbT + ((size_t)bh * D_ + d0 + d) * L_ + k0 + ck;
        u16x8 o0, o1;
#pragma unroll
        for (int j = 0; j < 8; ++j) o0[j] = f2bf(s[ck + j][d]);
#pragma unroll
        for (int j = 0; j < 8; ++j) o1[j] = f2bf(s[ck + 8 + j][d]);
        *(u16x8*)dst = o0;
        *(u16x8*)(dst + 8) = o1;
    }
}

// Single-source convert (Wp, after QKV GEMM frees its slot).
__global__ __launch_bounds__(256) void convert_bf16_kernel(
        const float* __restrict__ in, u16* __restrict__ out) {
    int i = blockIdx.x * 256 + threadIdx.x;
    const float4* p = (const float4*)in;
    float4 a = p[i * 2], b = p[i * 2 + 1];
    ((u16x8*)out)[i] = u16x8{f2bf(a.x), f2bf(a.y), f2bf(a.z), f2bf(a.w),
                             f2bf(b.x), f2bf(b.y), f2bf(b.z), f2bf(b.w)};
}

// ---------------------------------------------------------------------------
// Fused QKV NT GEMM, 2-phase double-buffered pipeline (T3 minimum recipe):
// prefetch K-step kt+32 issued BEFORE the MFMA on kt; single barrier per
// K-step (its implicit vmcnt(0) lands after the MFMA -> load latency hidden).
// C[m,n] = sum_k xb[m,k]*W[n,k]. N-space = [K | V | Q] regions of 2048 cols.
__global__ __launch_bounds__(256) void gemm_qkv(
        const u16* __restrict__ A,
        const u16* __restrict__ wbK, const u16* __restrict__ wbV,
        const u16* __restrict__ wbQ,
        float* __restrict__ kout, float* __restrict__ vout,
        u16* __restrict__ kb, u16* __restrict__ vbT, u16* __restrict__ Qst) {
    __shared__ u16 As[2][128 * 32];
    __shared__ u16 Bs[2][128 * 32];
    const int tid  = threadIdx.x;
    const int wave = tid >> 6;
    const int lane = tid & 63;
    const int m0   = blockIdx.y * 128;
    const int n0g  = blockIdx.x * 128;
    const int region = n0g >> 11;            // 0=K 1=V 2=Q
    const int n0   = n0g & 2047;
    const u16* Bw = (region == 0) ? wbK : (region == 1) ? wbV : wbQ;

    f32x4 acc[4][4];
#pragma unroll
    for (int i = 0; i < 4; ++i)
#pragma unroll
        for (int j = 0; j < 4; ++j) acc[i][j] = f32x4{0.f, 0.f, 0.f, 0.f};

    const int srow = lane >> 2;
    const int scol = (lane & 3) * 8;
    const int q0 = wave * 2, q1 = wave * 2 + 1;
    const u16* A0 = A  + (size_t)(m0 + q0 * 16 + srow) * C_ + scol;
    const u16* A1 = A  + (size_t)(m0 + q1 * 16 + srow) * C_ + scol;
    const u16* B0 = Bw + (size_t)(n0 + q0 * 16 + srow) * C_ + scol;
    const u16* B1 = Bw + (size_t)(n0 + q1 * 16 + srow) * C_ + scol;

    const int frow = lane & 15;
    const int fko  = (lane >> 4) * 8;
    const int wr = (wave >> 1) * 64;
    const int wc = (wave & 1) * 64;

    // prologue: stage kt=0 into buf 0
    gload_lds16(A0, &As[0][q0 * 512]);
    gload_lds16(A1, &As[0][q1 * 512]);
    gload_lds16(B0, &Bs[0][q0 * 512]);
    gload_lds16(B1, &Bs[0][q1 * 512]);
    __syncthreads();

    int cur = 0;
    for (int kt = 0; kt < C_; kt += 32) {
        const int nxt = cur ^ 1;
        if (kt + 32 < C_) {   // issue next-tile loads (latency hides under MFMA)
            gload_lds16(A0 + kt + 32, &As[nxt][q0 * 512]);
            gload_lds16(A1 + kt + 32, &As[nxt][q1 * 512]);
            gload_lds16(B0 + kt + 32, &Bs[nxt][q0 * 512]);
            gload_lds16(B1 + kt + 32, &Bs[nxt][q1 * 512]);
        }
        short8 af[4], bf[4];
#pragma unroll
        for (int i = 0; i < 4; ++i) {
            af[i] = *(const short8*)&As[cur][(wr + i * 16 + frow) * 32 + fko];
            bf[i] = *(const short8*)&Bs[cur][(wc + i * 16 + frow) * 32 + fko];
        }
#pragma unroll
        for (int mi = 0; mi < 4; ++mi)
#pragma unroll
            for (int ni = 0; ni < 4; ++ni)
                acc[mi][ni] = __builtin_amdgcn_mfma_f32_16x16x32_bf16(
                    af[mi], bf[ni], acc[mi][ni], 0, 0, 0);
        __syncthreads();   // drains vmcnt(0): prefetch complete, reads done
        cur = nxt;
    }

    const int ccol = lane & 15;
    const int crb  = (lane >> 4) * 4;
#pragma unroll
    for (int mi = 0; mi < 4; ++mi) {
#pragma unroll
        for (int ni = 0; ni < 4; ++ni) {
            const int gc  = n0 + wc + ni * 16 + ccol;
            const int grb = m0 + wr + mi * 16 + crb;
            if (region == 2) {
#pragma unroll
                for (int r = 0; r < 4; ++r)
                    Qst[(size_t)(grb + r) * C_ + gc] = f2bf(acc[mi][ni][r]);
            } else {
                const int b = grb >> 10, tb = grb & 1023;
                const int h = gc >> 7,  d  = gc & 127;
                const size_t fb = (((size_t)(b * H_ + h)) * L_ + P_ + tb) * D_ + d;
                if (region == 0) {
#pragma unroll
                    for (int r = 0; r < 4; ++r) {
                        kout[fb + (size_t)r * D_] = acc[mi][ni][r];
                        kb[fb + (size_t)r * D_]   = f2bf(acc[mi][ni][r]);
                    }
                } else {
#pragma unroll
                    for (int r = 0; r < 4; ++r) vout[fb + (size_t)r * D_] = acc[mi][ni][r];
                    const size_t tb2 = (((size_t)(b * H_ + h)) * D_ + d) * L_ + P_ + tb;
                    *(u16x4*)&vbT[tb2] = u16x4{
                        f2bf(acc[mi][ni][0]), f2bf(acc[mi][ni][1]),
                        f2bf(acc[mi][ni][2]), f2bf(acc[mi][ni][3])};
                }
            }
        }
    }
}

// ---------------------------------------------------------------------------
// Plain NT GEMM, same 2-phase pipeline. MODE 0: bf16 out. MODE 2: f32 + bias.
template <int MODE>
__global__ __launch_bounds__(256) void gemm128(
        const u16* __restrict__ A, const u16* __restrict__ Bw,
        float* __restrict__ outf, u16* __restrict__ outb,
        const float* __restrict__ bias) {
    __shared__ u16 As[2][128 * 32];
    __shared__ u16 Bs[2][128 * 32];
    const int tid  = threadIdx.x;
    const int wave = tid >> 6;
    const int lane = tid & 63;
    const int m0 = blockIdx.y * 128;
    const int n0 = blockIdx.x * 128;

    f32x4 acc[4][4];
#pragma unroll
    for (int i = 0; i < 4; ++i)
#pragma unroll
        for (int j = 0; j < 4; ++j) acc[i][j] = f32x4{0.f, 0.f, 0.f, 0.f};

    const int srow = lane >> 2;
    const int scol = (lane & 3) * 8;
    const int q0 = wave * 2, q1 = wave * 2 + 1;
    const u16* A0 = A  + (size_t)(m0 + q0 * 16 + srow) * C_ + scol;
    const u16* A1 = A  + (size_t)(m0 + q1 * 16 + srow) * C_ + scol;
    const u16* B0 = Bw + (size_t)(n0 + q0 * 16 + srow) * C_ + scol;
    const u16* B1 = Bw + (size_t)(n0 + q1 * 16 + srow) * C_ + scol;

    const int frow = lane & 15;
    const int fko  = (lane >> 4) * 8;
    const int wr = (wave >> 1) * 64;
    const int wc = (wave & 1) * 64;

    gload_lds16(A0, &As[0][q0 * 512]);
    gload_lds16(A1, &As[0][q1 * 512]);
    gload_lds16(B0, &Bs[0][q0 * 512]);
    gload_lds16(B1, &Bs[0][q1 * 512]);
    __syncthreads();

    int cur = 0;
    for (int kt = 0; kt < C_; kt += 32) {
        const int nxt = cur ^ 1;
        if (kt + 32 < C_) {
            gload_lds16(A0 + kt + 32, &As[nxt][q0 * 512]);
            gload_lds16(A1 + kt + 32, &As[nxt][q1 * 512]);
            gload_lds16(B0 + kt + 32, &Bs[nxt][q0 * 512]);
            gload_lds16(B1 + kt + 32, &Bs[nxt][q1 * 512]);
        }
        short8 af[4], bf[4];
#pragma unroll
        for (int i = 0; i < 4; ++i) {
            af[i] = *(const short8*)&As[cur][(wr + i * 16 + frow) * 32 + fko];
            bf[i] = *(const short8*)&Bs[cur][(wc + i * 16 + frow) * 32 + fko];
        }
#pragma unroll
        for (int mi = 0; mi < 4; ++mi)
#pragma unroll
            for (int ni = 0; ni < 4; ++ni)
                acc[mi][ni] = __builtin_amdgcn_mfma_f32_16x16x32_bf16(
                    af[mi], bf[ni], acc[mi][ni], 0, 0, 0);
        __syncthreads();
        cur = nxt;
    }

    const int ccol = lane & 15;
    const int crb  = (lane >> 4) * 4;
#pragma unroll
    for (int mi = 0; mi < 4; ++mi) {
#pragma unroll
        for (int ni = 0; ni < 4; ++ni) {
            const int gc  = n0 + wc + ni * 16 + ccol;
            const int grb = m0 + wr + mi * 16 + crb;
            if (MODE == 0) {
#pragma unroll
                for (int r = 0; r < 4; ++r)
                    outb[(size_t)(grb + r) * C_ + gc] = f2bf(acc[mi][ni][r]);
            } else {
                const float ba = bias[gc];
#pragma unroll
                for (int r = 0; r < 4; ++r)
                    outf[(size_t)(grb + r) * C_ + gc] = acc[mi][ni][r] + ba;
            }
        }
    }
}

// ---------------------------------------------------------------------------
// MFMA flash attention. One block = (b, h, 64 q-rows). K/V chunks of 64 keys.
// Q bf16 [B,T,C]; Kb bf16 [B,H,L,D]; VT bf16 [B,H,D,L]; O bf16 [B,T,C].
// Swizzled-source global_load_lds staging (conflict-free ds_read_b128).
// Softmax: round-1 form (defer-max reverted: it cost VGPR 88->124, +VALU).
#define NEG_BIG -30000.f
__global__ __launch_bounds__(256) void attn_kernel(
        const u16* __restrict__ Q, const u16* __restrict__ Kb,
        const u16* __restrict__ VT, u16* __restrict__ O) {
    __shared__ u16 Qs[64 * 128];   // [qrow][d]   swizzled
    __shared__ u16 Ks[64 * 128];   // [key][d]    swizzled
    __shared__ u16 Vs[128 * 64];   // [d][key]    swizzled (V^T)
    __shared__ u16 Ps[64][72];     // P tile

    const int tid  = threadIdx.x;
    const int wave = tid >> 6;
    const int lane = tid & 63;
    int       qt = blockIdx.x & 15;
    const int h  = (blockIdx.x >> 4) & 15;
    const int b  = blockIdx.x >> 8;
    // Load-balance: CU gets blocks c and c+256 (same qt, different b).
    // Flip qt for b=1 so each CU's pair sums to a uniform 49 chunks.
    if (b) qt = 15 - qt;
    const int t0 = qt * 64;

    const u16* Kbase = Kb + (size_t)(b * H_ + h) * L_ * D_;
    const u16* Vbase = VT + (size_t)(b * H_ + h) * D_ * L_;

    // Stage Q tile (64x128, 16 x 1KB issues, 4 per wave), swizzled source.
#pragma unroll
    for (int i = 0; i < 4; ++i) {
        int g   = (wave * 4 + i) * 64 + lane;   // 16B-block id 0..1023
        int row = g >> 4, blk = g & 15;
        int sb  = (blk & 8) | ((blk ^ row) & 7);
        gload_lds16(Q + ((size_t)(b * T_ + t0 + row)) * C_ + h * D_ + sb * 8,
                    &Qs[(wave * 4 + i) * 512]);
    }

    const int frow = lane & 15;
    const int quad = lane >> 4;
    const int fko  = quad * 8;
    const int swz  = (frow & 7) << 3;

    f32x4 o_acc[8];
#pragma unroll
    for (int n = 0; n < 8; ++n) o_acc[n] = f32x4{0.f, 0.f, 0.f, 0.f};
    float m_i[4] = {NEG_BIG, NEG_BIG, NEG_BIG, NEG_BIG};
    float l_i[4] = {0.f, 0.f, 0.f, 0.f};
    const float scale = 0.08838834764831845f;   // 1/sqrt(128)

    const int nch = (P_ + t0 + 64) >> 6;
    const int wave_lim = P_ + t0 + wave * 16 + 15;   // max key this wave attends

    for (int ch = 0; ch < nch; ++ch) {
        const int j0 = ch * 64;
        __syncthreads();   // prior iter's LDS consumers done (covers Q staging)
#pragma unroll
        for (int i = 0; i < 4; ++i) {
            int g = (wave * 4 + i) * 64 + lane;
            {   // K: 64 rows x 128 d, 16 blocks/row
                int row = g >> 4, blk = g & 15;
                int sb  = (blk & 8) | ((blk ^ row) & 7);
                gload_lds16(Kbase + (size_t)(j0 + row) * D_ + sb * 8,
                            &Ks[(wave * 4 + i) * 512]);
            }
            {   // V^T: 128 rows x 64 keys, 8 blocks/row
                int d  = g >> 3, cb = g & 7;
                int sb = (cb ^ d) & 7;
                gload_lds16(Vbase + (size_t)d * L_ + j0 + sb * 8,
                            &Vs[(wave * 4 + i) * 512]);
            }
        }
        __syncthreads();

        const bool active = (j0 <= wave_lim);   // any unmasked key for this wave?

        if (active) {
            // S = Q(wave's 16 rows) @ K^T  -> 4 col-tiles of 16 keys
            f32x4 st[4];
#pragma unroll
            for (int j = 0; j < 4; ++j) st[j] = f32x4{0.f, 0.f, 0.f, 0.f};
            __builtin_amdgcn_s_setprio(1);
#pragma unroll
            for (int kt = 0; kt < 4; ++kt) {
                short8 a = *(const short8*)&Qs[(wave * 16 + frow) * 128 +
                                               ((kt * 32 + fko) ^ swz)];
#pragma unroll
                for (int j = 0; j < 4; ++j) {
                    short8 kf = *(const short8*)&Ks[(j * 16 + frow) * 128 +
                                                    ((kt * 32 + fko) ^ swz)];
                    st[j] = __builtin_amdgcn_mfma_f32_16x16x32_bf16(a, kf, st[j], 0, 0, 0);
                }
            }
            __builtin_amdgcn_s_setprio(0);

            // Online softmax (round-1 form). Lane: rows quad*4+r, col frow+16j.
#pragma unroll
            for (int r = 0; r < 4; ++r) {
                const int t   = t0 + wave * 16 + quad * 4 + r;
                const int lim = P_ + t;
                float sv[4];
                float mx = NEG_BIG;
#pragma unroll
                for (int j = 0; j < 4; ++j) {
                    int jg = j0 + j * 16 + frow;
                    float s = st[j][r] * scale;
                    s = (jg <= lim) ? s : NEG_BIG;
                    sv[j] = s;
                    mx = fmaxf(mx, s);
                }
#pragma unroll
                for (int sft = 1; sft <= 8; sft <<= 1)
                    mx = fmaxf(mx, __shfl_xor(mx, sft, 64));
                float m_new = fmaxf(m_i[r], mx);
                float alpha = __expf(fminf(m_i[r] - m_new, 0.f));
                float rs = 0.f;
#pragma unroll
                for (int j = 0; j < 4; ++j) {
                    float p = __expf(fminf(sv[j] - m_new, 0.f));
                    p = (sv[j] <= NEG_BIG) ? 0.f : p;   // masked -> exactly 0
                    sv[j] = p;
                    rs += p;
                }
#pragma unroll
                for (int sft = 1; sft <= 8; sft <<= 1)
                    rs += __shfl_xor(rs, sft, 64);
                l_i[r] = l_i[r] * alpha + rs;
                m_i[r] = m_new;
#pragma unroll
                for (int n = 0; n < 8; ++n) o_acc[n][r] *= alpha;
#pragma unroll
                for (int j = 0; j < 4; ++j)
                    Ps[wave * 16 + quad * 4 + r][j * 16 + frow] = f2bf(sv[j]);
            }
        }
        __syncthreads();   // Ps stores visible (all waves reach this)

        if (active) {
            // PV: O(16x128) += P(16x64) @ V(64x128), B-operand from swizzled V^T.
            __builtin_amdgcn_s_setprio(1);
#pragma unroll
            for (int kt2 = 0; kt2 < 2; ++kt2) {
                short8 a = *(const short8*)&Ps[wave * 16 + frow][kt2 * 32 + fko];
#pragma unroll
                for (int n = 0; n < 8; ++n) {
                    short8 vf = *(const short8*)&Vs[(n * 16 + frow) * 64 +
                                                    ((kt2 * 32 + fko) ^ swz)];
                    o_acc[n] = __builtin_amdgcn_mfma_f32_16x16x32_bf16(a, vf, o_acc[n], 0, 0, 0);
                }
            }
            __builtin_amdgcn_s_setprio(0);
        }
    }

    // Epilogue: O /= l, store bf16 [B,T,C]
#pragma unroll
    for (int r = 0; r < 4; ++r) {
        float rl = 1.f / fmaxf(l_i[r], 1e-30f);
        int t = t0 + wave * 16 + quad * 4 + r;
#pragma unroll
        for (int n = 0; n < 8; ++n) {
            float v = o_acc[n][r] * rl;
            O[((size_t)(b * T_ + t)) * C_ + h * D_ + n * 16 + frow] = f2bf(v);
        }
    }
}

// ---------------------------------------------------------------------------
extern "C" void kernel_launch(void* const* d_in, const int* in_sizes, int n_in,
                              void* d_out, int out_size, void* d_ws, size_t ws_size,
                              hipStream_t stream) {
    const float* x      = (const float*)d_in[0];
    const float* past_k = (const float*)d_in[1];
    const float* past_v = (const float*)d_in[2];
    const float* Wk     = (const float*)d_in[3];
    const float* Wq     = (const float*)d_in[4];
    const float* Wv     = (const float*)d_in[5];
    const float* Wp     = (const float*)d_in[6];
    const float* bp     = (const float*)d_in[7];

    float* out  = (float*)d_out;             // [B,T,C]    16 MB
    float* kout = out + 4194304;             // [B,H,L,D]  32 MB
    float* vout = kout + 8388608;            // [B,H,L,D]  32 MB

    // d_out scratch (dead until final GEMM writes out):
    u16* Qst = (u16*)d_out;                          //  8 MB bf16 Q (written by Q-GEMM)
    u16* xb  = (u16*)((char*)d_out + (8u << 20));    //  8 MB bf16 x
    // d_ws (proven >= 48 MiB):
    u16* OstWq = (u16*)d_ws;                         //  8 MB: Wq bf16, then attn out
    u16* kb    = (u16*)((char*)d_ws + (8u  << 20));  // 16 MB bf16 K cache [B,H,L,D]
    u16* vbT   = (u16*)((char*)d_ws + (24u << 20));  // 16 MB bf16 V^T cache [B,H,D,L]
    u16* wbKP  = (u16*)((char*)d_ws + (40u << 20));  //  8 MB: Wk bf16, then Wp bf16
    // If workspace allows, a 5th slot lets K,V,Q fuse into one 768-block GEMM.
    const bool fused = ws_size >= (size_t)(56u << 20);
    u16* wbV = fused ? (u16*)((char*)d_ws + (48u << 20))
                     : Qst;   // fallback: Wv parked in Qst slot (dead until Q-GEMM)

    prep_kernel<<<13312, 256, 0, stream>>>(
        x, Wk, Wv, Wq,
        (const float4*)past_k, (const float4*)past_v,
        xb, wbKP, wbV, OstWq,
        (float4*)kout, (float4*)vout, (u16x4*)kb, vbT);

    if (fused) {
        dim3 g(48, 16);   // K | V | Q regions, 768 blocks (~3/CU)
        gemm_qkv<<<g, 256, 0, stream>>>(xb, wbKP, wbV, OstWq,
                                        kout, vout, kb, vbT, Qst);
    } else {
        dim3 gkv(32, 16); // K | V regions, 512 blocks (~2/CU)
        gemm_qkv<<<gkv, 256, 0, stream>>>(xb, wbKP, wbV, OstWq,
                                          kout, vout, kb, vbT, Qst);
        dim3 gq(16, 16);
        gemm128<0><<<gq, 256, 0, stream>>>(xb, OstWq, nullptr, Qst, nullptr);
    }

    attn_kernel<<<512, 256, 0, stream>>>(Qst, kb, vbT, OstWq);

    convert_bf16_kernel<<<2048, 256, 0, stream>>>(Wp, wbKP);
    dim3 gp(16, 16);
    gemm128<2><<<gp, 256, 0, stream>>>(OstWq, wbKP, out, nullptr, bp);
}

// Round 5
// 386.278 us; speedup vs baseline: 1.9057x; 1.0886x over previous
//
#include <hip/hip_runtime.h>
#include <stdint.h>

#define B_ 2
#define T_ 1024
#define C_ 2048
#define H_ 16
#define D_ 128
#define P_ 1024
#define L_ 2048   // P + T
#define M_ 2048   // B*T

typedef unsigned short u16;
typedef __attribute__((ext_vector_type(8))) short short8;   // MFMA A/B frag (8 bf16)
typedef __attribute__((ext_vector_type(4))) float f32x4;    // MFMA C/D frag
typedef __attribute__((ext_vector_type(8))) u16 u16x8;      // 16B vector
typedef __attribute__((ext_vector_type(4))) u16 u16x4;      // 8B vector

__device__ __forceinline__ u16 f2bf(float x) {
    union { float f; uint32_t u; } c; c.f = x;
    uint32_t u = c.u;
    return (u16)((u + 0x7fffu + ((u >> 16) & 1u)) >> 16);   // RNE
}

// Async global->LDS, 16B per lane. LDS dest = uniform base + lane*16 (HW rule).
__device__ __forceinline__ void gload_lds16(const void* g, void* l) {
    typedef __attribute__((address_space(1))) const void gvoid;
    typedef __attribute__((address_space(3))) void lvoid;
    __builtin_amdgcn_global_load_lds((gvoid*)g, (lvoid*)l, 16, 0, 0);
}

// ---------------------------------------------------------------------------
// Fused prep: one launch, region-dispatched.
//   [0,8192):      f32->bf16 convert of x, Wk, Wv, Wq (2048 blocks each)
//   [8192,12288):  past_k/past_v -> f32 caches + kb bf16 cache
//   [12288,13312): past_v -> vbT [B,H,D,L] bf16 (64x64 LDS transpose)
//   [13312,15360): f32->bf16 convert of Wp (only launched when ws has a slot)
__global__ __launch_bounds__(256) void prep_kernel(
        const float* __restrict__ x,  const float* __restrict__ wk,
        const float* __restrict__ wv, const float* __restrict__ wq,
        const float* __restrict__ wp,
        const float4* __restrict__ pk, const float4* __restrict__ pv,
        u16* __restrict__ xb, u16* __restrict__ obK,
        u16* __restrict__ obV, u16* __restrict__ obQ, u16* __restrict__ obP,
        float4* __restrict__ kdst, float4* __restrict__ vdst,
        u16x4* __restrict__ kb, u16* __restrict__ vbT) {
    __shared__ float s[64][65];
    const int bid = blockIdx.x;
    const int tid = threadIdx.x;
    if (bid < 8192) {
        const int r = bid >> 11;
        const int i = (bid & 2047) * 256 + tid;
        const float* src = (r == 0) ? x : (r == 1) ? wk : (r == 2) ? wv : wq;
        u16* dst = (r == 0) ? xb : (r == 1) ? obK : (r == 2) ? obV : obQ;
        float4 a = ((const float4*)src)[i * 2], b = ((const float4*)src)[i * 2 + 1];
        ((u16x8*)dst)[i] = u16x8{f2bf(a.x), f2bf(a.y), f2bf(a.z), f2bf(a.w),
                                 f2bf(b.x), f2bf(b.y), f2bf(b.z), f2bf(b.w)};
    } else if (bid < 12288) {
        const int i = (bid - 8192) * 256 + tid;    // float4 idx; total 1048576
        const int bh = i >> 15;                    // / (P*D/4 = 32768)
        const int rest = i & 32767;
        const size_t dst = (size_t)bh * (L_ * D_ / 4) + rest;
        float4 k4 = pk[i], v4 = pv[i];
        kdst[dst] = k4;
        vdst[dst] = v4;
        kb[dst] = u16x4{f2bf(k4.x), f2bf(k4.y), f2bf(k4.z), f2bf(k4.w)};
    } else if (bid < 13312) {
        const int tb = bid - 12288;                // 0..1023
        const int bh = tb >> 5;                    // 32 tiles per (b,h)
        const int tile = tb & 31;
        const int k0 = (tile >> 1) * 64;           // 16 k-tiles
        const int d0 = (tile & 1) * 64;            // 2 d-tiles
        const float* src = (const float*)pv + ((size_t)bh * P_ + k0) * D_ + d0;
        {
            int r = tid >> 2, c0 = (tid & 3) * 16;
#pragma unroll
            for (int u = 0; u < 4; ++u) {
                float4 f = *(const float4*)(src + (size_t)r * D_ + c0 + u * 4);
                s[r][c0 + u * 4 + 0] = f.x; s[r][c0 + u * 4 + 1] = f.y;
                s[r][c0 + u * 4 + 2] = f.z; s[r][c0 + u * 4 + 3] = f.w;
            }
        }
        __syncthreads();
        int d = tid >> 2, ck = (tid & 3) * 16;
        u16* dst = vbT + ((size_t)bh * D_ + d0 + d) * L_ + k0 + ck;
        u16x8 o0, o1;
#pragma unroll
        for (int j = 0; j < 8; ++j) o0[j] = f2bf(s[ck + j][d]);
#pragma unroll
        for (int j = 0; j < 8; ++j) o1[j] = f2bf(s[ck + 8 + j][d]);
        *(u16x8*)dst = o0;
        *(u16x8*)(dst + 8) = o1;
    } else {
        const int i = (bid - 13312) * 256 + tid;
        float4 a = ((const float4*)wp)[i * 2], b = ((const float4*)wp)[i * 2 + 1];
        ((u16x8*)obP)[i] = u16x8{f2bf(a.x), f2bf(a.y), f2bf(a.z), f2bf(a.w),
                                 f2bf(b.x), f2bf(b.y), f2bf(b.z), f2bf(b.w)};
    }
}

// Single-source convert (Wp fallback path, after QKV GEMM frees its slot).
__global__ __launch_bounds__(256) void convert_bf16_kernel(
        const float* __restrict__ in, u16* __restrict__ out) {
    int i = blockIdx.x * 256 + threadIdx.x;
    const float4* p = (const float4*)in;
    float4 a = p[i * 2], b = p[i * 2 + 1];
    ((u16x8*)out)[i] = u16x8{f2bf(a.x), f2bf(a.y), f2bf(a.z), f2bf(a.w),
                             f2bf(b.x), f2bf(b.y), f2bf(b.z), f2bf(b.w)};
}

// ---------------------------------------------------------------------------
// 3-buffer counted-vmcnt K-loop (T4): stage(t) and stage(t+1) in flight;
// each step waits only the OLDEST stage (vmcnt(4) = 4 loads of t+1 still out),
// raw s_barrier (no drain-to-0), then issues stage(t+2). Loads get ~2 K-steps
// of MFMA to land instead of <1 (m233: the vmcnt-0 drain was 72% of 2-phase).
// Safety: buf(t+2) was last read at step t-1; every wave's t-1 ds_reads
// completed (lgkmcnt before MFMA) before it reached barrier(t).

// Fused QKV NT GEMM: C[m,n] = sum_k xb[m,k]*W[n,k]. N-space = [K | V | Q].
__global__ __launch_bounds__(256) void gemm_qkv(
        const u16* __restrict__ A,
        const u16* __restrict__ wbK, const u16* __restrict__ wbV,
        const u16* __restrict__ wbQ,
        float* __restrict__ kout, float* __restrict__ vout,
        u16* __restrict__ kb, u16* __restrict__ vbT, u16* __restrict__ Qst) {
    __shared__ u16 As[3][128 * 32];
    __shared__ u16 Bs[3][128 * 32];
    const int tid  = threadIdx.x;
    const int wave = tid >> 6;
    const int lane = tid & 63;
    const int m0   = blockIdx.y * 128;
    const int n0g  = blockIdx.x * 128;
    const int region = n0g >> 11;            // 0=K 1=V 2=Q
    const int n0   = n0g & 2047;
    const u16* Bw = (region == 0) ? wbK : (region == 1) ? wbV : wbQ;

    f32x4 acc[4][4];
#pragma unroll
    for (int i = 0; i < 4; ++i)
#pragma unroll
        for (int j = 0; j < 4; ++j) acc[i][j] = f32x4{0.f, 0.f, 0.f, 0.f};

    const int srow = lane >> 2;
    const int scol = (lane & 3) * 8;
    const int q0 = wave * 2, q1 = wave * 2 + 1;
    const u16* A0 = A  + (size_t)(m0 + q0 * 16 + srow) * C_ + scol;
    const u16* A1 = A  + (size_t)(m0 + q1 * 16 + srow) * C_ + scol;
    const u16* B0 = Bw + (size_t)(n0 + q0 * 16 + srow) * C_ + scol;
    const u16* B1 = Bw + (size_t)(n0 + q1 * 16 + srow) * C_ + scol;

    const int frow = lane & 15;
    const int fko  = (lane >> 4) * 8;
    const int wr = (wave >> 1) * 64;
    const int wc = (wave & 1) * 64;

    u16 *Ac = &As[0][0], *An = &As[1][0], *Af = &As[2][0];
    u16 *Bc = &Bs[0][0], *Bn = &Bs[1][0], *Bf = &Bs[2][0];

    // prologue: stage kt=0 -> buf0, kt=32 -> buf1 (8 loads in flight/wave)
    gload_lds16(A0,      Ac + q0 * 512);
    gload_lds16(A1,      Ac + q1 * 512);
    gload_lds16(B0,      Bc + q0 * 512);
    gload_lds16(B1,      Bc + q1 * 512);
    gload_lds16(A0 + 32, An + q0 * 512);
    gload_lds16(A1 + 32, An + q1 * 512);
    gload_lds16(B0 + 32, Bn + q0 * 512);
    gload_lds16(B1 + 32, Bn + q1 * 512);

    for (int kt = 0; kt < C_ - 32; kt += 32) {
        asm volatile("s_waitcnt vmcnt(4)" ::: "memory");  // stage(kt) landed
        __builtin_amdgcn_s_barrier();                     // all waves' stage(kt) landed
        asm volatile("" ::: "memory");
        if (kt + 64 < C_) {                               // issue stage(kt+64)
            gload_lds16(A0 + kt + 64, Af + q0 * 512);
            gload_lds16(A1 + kt + 64, Af + q1 * 512);
            gload_lds16(B0 + kt + 64, Bf + q0 * 512);
            gload_lds16(B1 + kt + 64, Bf + q1 * 512);
        }
        short8 af[4], bf[4];
#pragma unroll
        for (int i = 0; i < 4; ++i) {
            af[i] = *(const short8*)&Ac[(wr + i * 16 + frow) * 32 + fko];
            bf[i] = *(const short8*)&Bc[(wc + i * 16 + frow) * 32 + fko];
        }
#pragma unroll
        for (int mi = 0; mi < 4; ++mi)
#pragma unroll
            for (int ni = 0; ni < 4; ++ni)
                acc[mi][ni] = __builtin_amdgcn_mfma_f32_16x16x32_bf16(
                    af[mi], bf[ni], acc[mi][ni], 0, 0, 0);
        u16* t;
        t = Ac; Ac = An; An = Af; Af = t;
        t = Bc; Bc = Bn; Bn = Bf; Bf = t;
    }
    {   // final K-step (kt = C_-32): only its own 4 loads in flight
        asm volatile("s_waitcnt vmcnt(0)" ::: "memory");
        __builtin_amdgcn_s_barrier();
        asm volatile("" ::: "memory");
        short8 af[4], bf[4];
#pragma unroll
        for (int i = 0; i < 4; ++i) {
            af[i] = *(const short8*)&Ac[(wr + i * 16 + frow) * 32 + fko];
            bf[i] = *(const short8*)&Bc[(wc + i * 16 + frow) * 32 + fko];
        }
#pragma unroll
        for (int mi = 0; mi < 4; ++mi)
#pragma unroll
            for (int ni = 0; ni < 4; ++ni)
                acc[mi][ni] = __builtin_amdgcn_mfma_f32_16x16x32_bf16(
                    af[mi], bf[ni], acc[mi][ni], 0, 0, 0);
    }

    const int ccol = lane & 15;
    const int crb  = (lane >> 4) * 4;
#pragma unroll
    for (int mi = 0; mi < 4; ++mi) {
#pragma unroll
        for (int ni = 0; ni < 4; ++ni) {
            const int gc  = n0 + wc + ni * 16 + ccol;
            const int grb = m0 + wr + mi * 16 + crb;
            if (region == 2) {
#pragma unroll
                for (int r = 0; r < 4; ++r)
                    Qst[(size_t)(grb + r) * C_ + gc] = f2bf(acc[mi][ni][r]);
            } else {
                const int b = grb >> 10, tb = grb & 1023;
                const int h = gc >> 7,  d  = gc & 127;
                const size_t fb = (((size_t)(b * H_ + h)) * L_ + P_ + tb) * D_ + d;
                if (region == 0) {
#pragma unroll
                    for (int r = 0; r < 4; ++r) {
                        kout[fb + (size_t)r * D_] = acc[mi][ni][r];
                        kb[fb + (size_t)r * D_]   = f2bf(acc[mi][ni][r]);
                    }
                } else {
#pragma unroll
                    for (int r = 0; r < 4; ++r) vout[fb + (size_t)r * D_] = acc[mi][ni][r];
                    const size_t tb2 = (((size_t)(b * H_ + h)) * D_ + d) * L_ + P_ + tb;
                    *(u16x4*)&vbT[tb2] = u16x4{
                        f2bf(acc[mi][ni][0]), f2bf(acc[mi][ni][1]),
                        f2bf(acc[mi][ni][2]), f2bf(acc[mi][ni][3])};
                }
            }
        }
    }
}

// ---------------------------------------------------------------------------
// Plain NT GEMM, same pipeline. MODE 0: bf16 out. MODE 2: f32 + bias.
template <int MODE>
__global__ __launch_bounds__(256) void gemm128(
        const u16* __restrict__ A, const u16* __restrict__ Bw,
        float* __restrict__ outf, u16* __restrict__ outb,
        const float* __restrict__ bias) {
    __shared__ u16 As[3][128 * 32];
    __shared__ u16 Bs[3][128 * 32];
    const int tid  = threadIdx.x;
    const int wave = tid >> 6;
    const int lane = tid & 63;
    const int m0 = blockIdx.y * 128;
    const int n0 = blockIdx.x * 128;

    f32x4 acc[4][4];
#pragma unroll
    for (int i = 0; i < 4; ++i)
#pragma unroll
        for (int j = 0; j < 4; ++j) acc[i][j] = f32x4{0.f, 0.f, 0.f, 0.f};

    const int srow = lane >> 2;
    const int scol = (lane & 3) * 8;
    const int q0 = wave * 2, q1 = wave * 2 + 1;
    const u16* A0 = A  + (size_t)(m0 + q0 * 16 + srow) * C_ + scol;
    const u16* A1 = A  + (size_t)(m0 + q1 * 16 + srow) * C_ + scol;
    const u16* B0 = Bw + (size_t)(n0 + q0 * 16 + srow) * C_ + scol;
    const u16* B1 = Bw + (size_t)(n0 + q1 * 16 + srow) * C_ + scol;

    const int frow = lane & 15;
    const int fko  = (lane >> 4) * 8;
    const int wr = (wave >> 1) * 64;
    const int wc = (wave & 1) * 64;

    u16 *Ac = &As[0][0], *An = &As[1][0], *Af = &As[2][0];
    u16 *Bc = &Bs[0][0], *Bn = &Bs[1][0], *Bf = &Bs[2][0];

    gload_lds16(A0,      Ac + q0 * 512);
    gload_lds16(A1,      Ac + q1 * 512);
    gload_lds16(B0,      Bc + q0 * 512);
    gload_lds16(B1,      Bc + q1 * 512);
    gload_lds16(A0 + 32, An + q0 * 512);
    gload_lds16(A1 + 32, An + q1 * 512);
    gload_lds16(B0 + 32, Bn + q0 * 512);
    gload_lds16(B1 + 32, Bn + q1 * 512);

    for (int kt = 0; kt < C_ - 32; kt += 32) {
        asm volatile("s_waitcnt vmcnt(4)" ::: "memory");
        __builtin_amdgcn_s_barrier();
        asm volatile("" ::: "memory");
        if (kt + 64 < C_) {
            gload_lds16(A0 + kt + 64, Af + q0 * 512);
            gload_lds16(A1 + kt + 64, Af + q1 * 512);
            gload_lds16(B0 + kt + 64, Bf + q0 * 512);
            gload_lds16(B1 + kt + 64, Bf + q1 * 512);
        }
        short8 af[4], bf[4];
#pragma unroll
        for (int i = 0; i < 4; ++i) {
            af[i] = *(const short8*)&Ac[(wr + i * 16 + frow) * 32 + fko];
            bf[i] = *(const short8*)&Bc[(wc + i * 16 + frow) * 32 + fko];
        }
#pragma unroll
        for (int mi = 0; mi < 4; ++mi)
#pragma unroll
            for (int ni = 0; ni < 4; ++ni)
                acc[mi][ni] = __builtin_amdgcn_mfma_f32_16x16x32_bf16(
                    af[mi], bf[ni], acc[mi][ni], 0, 0, 0);
        u16* t;
        t = Ac; Ac = An; An = Af; Af = t;
        t = Bc; Bc = Bn; Bn = Bf; Bf = t;
    }
    {
        asm volatile("s_waitcnt vmcnt(0)" ::: "memory");
        __builtin_amdgcn_s_barrier();
        asm volatile("" ::: "memory");
        short8 af[4], bf[4];
#pragma unroll
        for (int i = 0; i < 4; ++i) {
            af[i] = *(const short8*)&Ac[(wr + i * 16 + frow) * 32 + fko];
            bf[i] = *(const short8*)&Bc[(wc + i * 16 + frow) * 32 + fko];
        }
#pragma unroll
        for (int mi = 0; mi < 4; ++mi)
#pragma unroll
            for (int ni = 0; ni < 4; ++ni)
                acc[mi][ni] = __builtin_amdgcn_mfma_f32_16x16x32_bf16(
                    af[mi], bf[ni], acc[mi][ni], 0, 0, 0);
    }

    const int ccol = lane & 15;
    const int crb  = (lane >> 4) * 4;
#pragma unroll
    for (int mi = 0; mi < 4; ++mi) {
#pragma unroll
        for (int ni = 0; ni < 4; ++ni) {
            const int gc  = n0 + wc + ni * 16 + ccol;
            const int grb = m0 + wr + mi * 16 + crb;
            if (MODE == 0) {
#pragma unroll
                for (int r = 0; r < 4; ++r)
                    outb[(size_t)(grb + r) * C_ + gc] = f2bf(acc[mi][ni][r]);
            } else {
                const float ba = bias[gc];
#pragma unroll
                for (int r = 0; r < 4; ++r)
                    outf[(size_t)(grb + r) * C_ + gc] = acc[mi][ni][r] + ba;
            }
        }
    }
}

// ---------------------------------------------------------------------------
// MFMA flash attention (unchanged from round 4). One block = (b,h,64 q-rows).
#define NEG_BIG -30000.f
__global__ __launch_bounds__(256) void attn_kernel(
        const u16* __restrict__ Q, const u16* __restrict__ Kb,
        const u16* __restrict__ VT, u16* __restrict__ O) {
    __shared__ u16 Qs[64 * 128];   // [qrow][d]   swizzled
    __shared__ u16 Ks[64 * 128];   // [key][d]    swizzled
    __shared__ u16 Vs[128 * 64];   // [d][key]    swizzled (V^T)
    __shared__ u16 Ps[64][72];     // P tile

    const int tid  = threadIdx.x;
    const int wave = tid >> 6;
    const int lane = tid & 63;
    int       qt = blockIdx.x & 15;
    const int h  = (blockIdx.x >> 4) & 15;
    const int b  = blockIdx.x >> 8;
    // Load-balance: CU gets blocks c and c+256 (same qt, different b).
    if (b) qt = 15 - qt;
    const int t0 = qt * 64;

    const u16* Kbase = Kb + (size_t)(b * H_ + h) * L_ * D_;
    const u16* Vbase = VT + (size_t)(b * H_ + h) * D_ * L_;

#pragma unroll
    for (int i = 0; i < 4; ++i) {
        int g   = (wave * 4 + i) * 64 + lane;   // 16B-block id 0..1023
        int row = g >> 4, blk = g & 15;
        int sb  = (blk & 8) | ((blk ^ row) & 7);
        gload_lds16(Q + ((size_t)(b * T_ + t0 + row)) * C_ + h * D_ + sb * 8,
                    &Qs[(wave * 4 + i) * 512]);
    }

    const int frow = lane & 15;
    const int quad = lane >> 4;
    const int fko  = quad * 8;
    const int swz  = (frow & 7) << 3;

    f32x4 o_acc[8];
#pragma unroll
    for (int n = 0; n < 8; ++n) o_acc[n] = f32x4{0.f, 0.f, 0.f, 0.f};
    float m_i[4] = {NEG_BIG, NEG_BIG, NEG_BIG, NEG_BIG};
    float l_i[4] = {0.f, 0.f, 0.f, 0.f};
    const float scale = 0.08838834764831845f;   // 1/sqrt(128)

    const int nch = (P_ + t0 + 64) >> 6;
    const int wave_lim = P_ + t0 + wave * 16 + 15;

    for (int ch = 0; ch < nch; ++ch) {
        const int j0 = ch * 64;
        __syncthreads();
#pragma unroll
        for (int i = 0; i < 4; ++i) {
            int g = (wave * 4 + i) * 64 + lane;
            {   // K: 64 rows x 128 d, 16 blocks/row
                int row = g >> 4, blk = g & 15;
                int sb  = (blk & 8) | ((blk ^ row) & 7);
                gload_lds16(Kbase + (size_t)(j0 + row) * D_ + sb * 8,
                            &Ks[(wave * 4 + i) * 512]);
            }
            {   // V^T: 128 rows x 64 keys, 8 blocks/row
                int d  = g >> 3, cb = g & 7;
                int sb = (cb ^ d) & 7;
                gload_lds16(Vbase + (size_t)d * L_ + j0 + sb * 8,
                            &Vs[(wave * 4 + i) * 512]);
            }
        }
        __syncthreads();

        const bool active = (j0 <= wave_lim);

        if (active) {
            f32x4 st[4];
#pragma unroll
            for (int j = 0; j < 4; ++j) st[j] = f32x4{0.f, 0.f, 0.f, 0.f};
            __builtin_amdgcn_s_setprio(1);
#pragma unroll
            for (int kt = 0; kt < 4; ++kt) {
                short8 a = *(const short8*)&Qs[(wave * 16 + frow) * 128 +
                                               ((kt * 32 + fko) ^ swz)];
#pragma unroll
                for (int j = 0; j < 4; ++j) {
                    short8 kf = *(const short8*)&Ks[(j * 16 + frow) * 128 +
                                                    ((kt * 32 + fko) ^ swz)];
                    st[j] = __builtin_amdgcn_mfma_f32_16x16x32_bf16(a, kf, st[j], 0, 0, 0);
                }
            }
            __builtin_amdgcn_s_setprio(0);

#pragma unroll
            for (int r = 0; r < 4; ++r) {
                const int t   = t0 + wave * 16 + quad * 4 + r;
                const int lim = P_ + t;
                float sv[4];
                float mx = NEG_BIG;
#pragma unroll
                for (int j = 0; j < 4; ++j) {
                    int jg = j0 + j * 16 + frow;
                    float s = st[j][r] * scale;
                    s = (jg <= lim) ? s : NEG_BIG;
                    sv[j] = s;
                    mx = fmaxf(mx, s);
                }
#pragma unroll
                for (int sft = 1; sft <= 8; sft <<= 1)
                    mx = fmaxf(mx, __shfl_xor(mx, sft, 64));
                float m_new = fmaxf(m_i[r], mx);
                float alpha = __expf(fminf(m_i[r] - m_new, 0.f));
                float rs = 0.f;
#pragma unroll
                for (int j = 0; j < 4; ++j) {
                    float p = __expf(fminf(sv[j] - m_new, 0.f));
                    p = (sv[j] <= NEG_BIG) ? 0.f : p;
                    sv[j] = p;
                    rs += p;
                }
#pragma unroll
                for (int sft = 1; sft <= 8; sft <<= 1)
                    rs += __shfl_xor(rs, sft, 64);
                l_i[r] = l_i[r] * alpha + rs;
                m_i[r] = m_new;
#pragma unroll
                for (int n = 0; n < 8; ++n) o_acc[n][r] *= alpha;
#pragma unroll
                for (int j = 0; j < 4; ++j)
                    Ps[wave * 16 + quad * 4 + r][j * 16 + frow] = f2bf(sv[j]);
            }
        }
        __syncthreads();

        if (active) {
            __builtin_amdgcn_s_setprio(1);
#pragma unroll
            for (int kt2 = 0; kt2 < 2; ++kt2) {
                short8 a = *(const short8*)&Ps[wave * 16 + frow][kt2 * 32 + fko];
#pragma unroll
                for (int n = 0; n < 8; ++n) {
                    short8 vf = *(const short8*)&Vs[(n * 16 + frow) * 64 +
                                                    ((kt2 * 32 + fko) ^ swz)];
                    o_acc[n] = __builtin_amdgcn_mfma_f32_16x16x32_bf16(a, vf, o_acc[n], 0, 0, 0);
                }
            }
            __builtin_amdgcn_s_setprio(0);
        }
    }

#pragma unroll
    for (int r = 0; r < 4; ++r) {
        float rl = 1.f / fmaxf(l_i[r], 1e-30f);
        int t = t0 + wave * 16 + quad * 4 + r;
#pragma unroll
        for (int n = 0; n < 8; ++n) {
            float v = o_acc[n][r] * rl;
            O[((size_t)(b * T_ + t)) * C_ + h * D_ + n * 16 + frow] = f2bf(v);
        }
    }
}

// ---------------------------------------------------------------------------
extern "C" void kernel_launch(void* const* d_in, const int* in_sizes, int n_in,
                              void* d_out, int out_size, void* d_ws, size_t ws_size,
                              hipStream_t stream) {
    const float* x      = (const float*)d_in[0];
    const float* past_k = (const float*)d_in[1];
    const float* past_v = (const float*)d_in[2];
    const float* Wk     = (const float*)d_in[3];
    const float* Wq     = (const float*)d_in[4];
    const float* Wv     = (const float*)d_in[5];
    const float* Wp     = (const float*)d_in[6];
    const float* bp     = (const float*)d_in[7];

    float* out  = (float*)d_out;             // [B,T,C]    16 MB
    float* kout = out + 4194304;             // [B,H,L,D]  32 MB
    float* vout = kout + 8388608;            // [B,H,L,D]  32 MB

    // d_out scratch (dead until final GEMM writes out):
    u16* Qst = (u16*)d_out;                          //  8 MB bf16 Q
    u16* xb  = (u16*)((char*)d_out + (8u << 20));    //  8 MB bf16 x
    // d_ws (proven >= 48 MiB):
    u16* OstWq = (u16*)d_ws;                         //  8 MB: Wq bf16, then attn out
    u16* kb    = (u16*)((char*)d_ws + (8u  << 20));  // 16 MB bf16 K cache [B,H,L,D]
    u16* vbT   = (u16*)((char*)d_ws + (24u << 20));  // 16 MB bf16 V^T cache [B,H,D,L]
    u16* wbKP  = (u16*)((char*)d_ws + (40u << 20));  //  8 MB: Wk bf16 (then Wp if !bigws)
    const bool fused = ws_size >= (size_t)(56u << 20);
    const bool bigws = ws_size >= (size_t)(64u << 20);
    u16* wbV = fused ? (u16*)((char*)d_ws + (48u << 20))
                     : Qst;   // fallback: Wv parked in Qst slot (dead until Q-GEMM)
    u16* wbP = bigws ? (u16*)((char*)d_ws + (56u << 20)) : wbKP;

    prep_kernel<<<bigws ? 15360 : 13312, 256, 0, stream>>>(
        x, Wk, Wv, Wq, Wp,
        (const float4*)past_k, (const float4*)past_v,
        xb, wbKP, wbV, OstWq, bigws ? wbP : nullptr,
        (float4*)kout, (float4*)vout, (u16x4*)kb, vbT);

    if (fused) {
        dim3 g(48, 16);   // K | V | Q regions, 768 blocks (~3/CU)
        gemm_qkv<<<g, 256, 0, stream>>>(xb, wbKP, wbV, OstWq,
                                        kout, vout, kb, vbT, Qst);
    } else {
        dim3 gkv(32, 16); // K | V regions, 512 blocks (~2/CU)
        gemm_qkv<<<gkv, 256, 0, stream>>>(xb, wbKP, wbV, OstWq,
                                          kout, vout, kb, vbT, Qst);
        dim3 gq(16, 16);
        gemm128<0><<<gq, 256, 0, stream>>>(xb, OstWq, nullptr, Qst, nullptr);
    }

    attn_kernel<<<512, 256, 0, stream>>>(Qst, kb, vbT, OstWq);

    if (!bigws) convert_bf16_kernel<<<2048, 256, 0, stream>>>(Wp, wbKP);
    dim3 gp(16, 16);
    gemm128<2><<<gp, 256, 0, stream>>>(OstWq, wbP, out, nullptr, bp);
}

// Round 6
// 384.257 us; speedup vs baseline: 1.9157x; 1.0053x over previous
//
#include <hip/hip_runtime.h>
#include <stdint.h>

#define B_ 2
#define T_ 1024
#define C_ 2048
#define H_ 16
#define D_ 128
#define P_ 1024
#define L_ 2048   // P + T
#define M_ 2048   // B*T

typedef unsigned short u16;
typedef __attribute__((ext_vector_type(8))) short short8;   // MFMA A/B frag (8 bf16)
typedef __attribute__((ext_vector_type(4))) float f32x4;    // MFMA C/D frag
typedef __attribute__((ext_vector_type(8))) u16 u16x8;      // 16B vector
typedef __attribute__((ext_vector_type(4))) u16 u16x4;      // 8B vector

__device__ __forceinline__ u16 f2bf(float x) {
    union { float f; uint32_t u; } c; c.f = x;
    uint32_t u = c.u;
    return (u16)((u + 0x7fffu + ((u >> 16) & 1u)) >> 16);   // RNE
}

// Async global->LDS, 16B per lane. LDS dest = uniform base + lane*16 (HW rule).
__device__ __forceinline__ void gload_lds16(const void* g, void* l) {
    typedef __attribute__((address_space(1))) const void gvoid;
    typedef __attribute__((address_space(3))) void lvoid;
    __builtin_amdgcn_global_load_lds((gvoid*)g, (lvoid*)l, 16, 0, 0);
}

// ---------------------------------------------------------------------------
// Fused prep: one launch, region-dispatched.
//   [0,8192):      f32->bf16 convert of x, Wk, Wv, Wq (2048 blocks each)
//   [8192,12288):  past_k/past_v -> f32 caches + kb bf16 cache
//   [12288,13312): past_v -> vbT [B,H,D,L] bf16 (64x64 LDS transpose)
//   [13312,15360): f32->bf16 convert of Wp (only launched when ws has a slot)
__global__ __launch_bounds__(256) void prep_kernel(
        const float* __restrict__ x,  const float* __restrict__ wk,
        const float* __restrict__ wv, const float* __restrict__ wq,
        const float* __restrict__ wp,
        const float4* __restrict__ pk, const float4* __restrict__ pv,
        u16* __restrict__ xb, u16* __restrict__ obK,
        u16* __restrict__ obV, u16* __restrict__ obQ, u16* __restrict__ obP,
        float4* __restrict__ kdst, float4* __restrict__ vdst,
        u16x4* __restrict__ kb, u16* __restrict__ vbT) {
    __shared__ float s[64][65];
    const int bid = blockIdx.x;
    const int tid = threadIdx.x;
    if (bid < 8192) {
        const int r = bid >> 11;
        const int i = (bid & 2047) * 256 + tid;
        const float* src = (r == 0) ? x : (r == 1) ? wk : (r == 2) ? wv : wq;
        u16* dst = (r == 0) ? xb : (r == 1) ? obK : (r == 2) ? obV : obQ;
        float4 a = ((const float4*)src)[i * 2], b = ((const float4*)src)[i * 2 + 1];
        ((u16x8*)dst)[i] = u16x8{f2bf(a.x), f2bf(a.y), f2bf(a.z), f2bf(a.w),
                                 f2bf(b.x), f2bf(b.y), f2bf(b.z), f2bf(b.w)};
    } else if (bid < 12288) {
        const int i = (bid - 8192) * 256 + tid;    // float4 idx; total 1048576
        const int bh = i >> 15;                    // / (P*D/4 = 32768)
        const int rest = i & 32767;
        const size_t dst = (size_t)bh * (L_ * D_ / 4) + rest;
        float4 k4 = pk[i], v4 = pv[i];
        kdst[dst] = k4;
        vdst[dst] = v4;
        kb[dst] = u16x4{f2bf(k4.x), f2bf(k4.y), f2bf(k4.z), f2bf(k4.w)};
    } else if (bid < 13312) {
        const int tb = bid - 12288;                // 0..1023
        const int bh = tb >> 5;                    // 32 tiles per (b,h)
        const int tile = tb & 31;
        const int k0 = (tile >> 1) * 64;           // 16 k-tiles
        const int d0 = (tile & 1) * 64;            // 2 d-tiles
        const float* src = (const float*)pv + ((size_t)bh * P_ + k0) * D_ + d0;
        {
            int r = tid >> 2, c0 = (tid & 3) * 16;
#pragma unroll
            for (int u = 0; u < 4; ++u) {
                float4 f = *(const float4*)(src + (size_t)r * D_ + c0 + u * 4);
                s[r][c0 + u * 4 + 0] = f.x; s[r][c0 + u * 4 + 1] = f.y;
                s[r][c0 + u * 4 + 2] = f.z; s[r][c0 + u * 4 + 3] = f.w;
            }
        }
        __syncthreads();
        int d = tid >> 2, ck = (tid & 3) * 16;
        u16* dst = vbT + ((size_t)bh * D_ + d0 + d) * L_ + k0 + ck;
        u16x8 o0, o1;
#pragma unroll
        for (int j = 0; j < 8; ++j) o0[j] = f2bf(s[ck + j][d]);
#pragma unroll
        for (int j = 0; j < 8; ++j) o1[j] = f2bf(s[ck + 8 + j][d]);
        *(u16x8*)dst = o0;
        *(u16x8*)(dst + 8) = o1;
    } else {
        const int i = (bid - 13312) * 256 + tid;
        float4 a = ((const float4*)wp)[i * 2], b = ((const float4*)wp)[i * 2 + 1];
        ((u16x8*)obP)[i] = u16x8{f2bf(a.x), f2bf(a.y), f2bf(a.z), f2bf(a.w),
                                 f2bf(b.x), f2bf(b.y), f2bf(b.z), f2bf(b.w)};
    }
}

// Single-source convert (Wp fallback path, after QKV GEMM frees its slot).
__global__ __launch_bounds__(256) void convert_bf16_kernel(
        const float* __restrict__ in, u16* __restrict__ out) {
    int i = blockIdx.x * 256 + threadIdx.x;
    const float4* p = (const float4*)in;
    float4 a = p[i * 2], b = p[i * 2 + 1];
    ((u16x8*)out)[i] = u16x8{f2bf(a.x), f2bf(a.y), f2bf(a.z), f2bf(a.w),
                             f2bf(b.x), f2bf(b.y), f2bf(b.z), f2bf(b.w)};
}

// ---------------------------------------------------------------------------
// 3-buffer counted-vmcnt K-loop (T4). Unchanged from round 5 (verified).
__global__ __launch_bounds__(256) void gemm_qkv(
        const u16* __restrict__ A,
        const u16* __restrict__ wbK, const u16* __restrict__ wbV,
        const u16* __restrict__ wbQ,
        float* __restrict__ kout, float* __restrict__ vout,
        u16* __restrict__ kb, u16* __restrict__ vbT, u16* __restrict__ Qst) {
    __shared__ u16 As[3][128 * 32];
    __shared__ u16 Bs[3][128 * 32];
    const int tid  = threadIdx.x;
    const int wave = tid >> 6;
    const int lane = tid & 63;
    const int m0   = blockIdx.y * 128;
    const int n0g  = blockIdx.x * 128;
    const int region = n0g >> 11;            // 0=K 1=V 2=Q
    const int n0   = n0g & 2047;
    const u16* Bw = (region == 0) ? wbK : (region == 1) ? wbV : wbQ;

    f32x4 acc[4][4];
#pragma unroll
    for (int i = 0; i < 4; ++i)
#pragma unroll
        for (int j = 0; j < 4; ++j) acc[i][j] = f32x4{0.f, 0.f, 0.f, 0.f};

    const int srow = lane >> 2;
    const int scol = (lane & 3) * 8;
    const int q0 = wave * 2, q1 = wave * 2 + 1;
    const u16* A0 = A  + (size_t)(m0 + q0 * 16 + srow) * C_ + scol;
    const u16* A1 = A  + (size_t)(m0 + q1 * 16 + srow) * C_ + scol;
    const u16* B0 = Bw + (size_t)(n0 + q0 * 16 + srow) * C_ + scol;
    const u16* B1 = Bw + (size_t)(n0 + q1 * 16 + srow) * C_ + scol;

    const int frow = lane & 15;
    const int fko  = (lane >> 4) * 8;
    const int wr = (wave >> 1) * 64;
    const int wc = (wave & 1) * 64;

    u16 *Ac = &As[0][0], *An = &As[1][0], *Af = &As[2][0];
    u16 *Bc = &Bs[0][0], *Bn = &Bs[1][0], *Bf = &Bs[2][0];

    gload_lds16(A0,      Ac + q0 * 512);
    gload_lds16(A1,      Ac + q1 * 512);
    gload_lds16(B0,      Bc + q0 * 512);
    gload_lds16(B1,      Bc + q1 * 512);
    gload_lds16(A0 + 32, An + q0 * 512);
    gload_lds16(A1 + 32, An + q1 * 512);
    gload_lds16(B0 + 32, Bn + q0 * 512);
    gload_lds16(B1 + 32, Bn + q1 * 512);

    for (int kt = 0; kt < C_ - 32; kt += 32) {
        asm volatile("s_waitcnt vmcnt(4)" ::: "memory");  // stage(kt) landed
        __builtin_amdgcn_s_barrier();                     // all waves' stage(kt) landed
        asm volatile("" ::: "memory");
        if (kt + 64 < C_) {                               // issue stage(kt+64)
            gload_lds16(A0 + kt + 64, Af + q0 * 512);
            gload_lds16(A1 + kt + 64, Af + q1 * 512);
            gload_lds16(B0 + kt + 64, Bf + q0 * 512);
            gload_lds16(B1 + kt + 64, Bf + q1 * 512);
        }
        short8 af[4], bf[4];
#pragma unroll
        for (int i = 0; i < 4; ++i) {
            af[i] = *(const short8*)&Ac[(wr + i * 16 + frow) * 32 + fko];
            bf[i] = *(const short8*)&Bc[(wc + i * 16 + frow) * 32 + fko];
        }
#pragma unroll
        for (int mi = 0; mi < 4; ++mi)
#pragma unroll
            for (int ni = 0; ni < 4; ++ni)
                acc[mi][ni] = __builtin_amdgcn_mfma_f32_16x16x32_bf16(
                    af[mi], bf[ni], acc[mi][ni], 0, 0, 0);
        u16* t;
        t = Ac; Ac = An; An = Af; Af = t;
        t = Bc; Bc = Bn; Bn = Bf; Bf = t;
    }
    {   // final K-step (kt = C_-32)
        asm volatile("s_waitcnt vmcnt(0)" ::: "memory");
        __builtin_amdgcn_s_barrier();
        asm volatile("" ::: "memory");
        short8 af[4], bf[4];
#pragma unroll
        for (int i = 0; i < 4; ++i) {
            af[i] = *(const short8*)&Ac[(wr + i * 16 + frow) * 32 + fko];
            bf[i] = *(const short8*)&Bc[(wc + i * 16 + frow) * 32 + fko];
        }
#pragma unroll
        for (int mi = 0; mi < 4; ++mi)
#pragma unroll
            for (int ni = 0; ni < 4; ++ni)
                acc[mi][ni] = __builtin_amdgcn_mfma_f32_16x16x32_bf16(
                    af[mi], bf[ni], acc[mi][ni], 0, 0, 0);
    }

    const int ccol = lane & 15;
    const int crb  = (lane >> 4) * 4;
#pragma unroll
    for (int mi = 0; mi < 4; ++mi) {
#pragma unroll
        for (int ni = 0; ni < 4; ++ni) {
            const int gc  = n0 + wc + ni * 16 + ccol;
            const int grb = m0 + wr + mi * 16 + crb;
            if (region == 2) {
#pragma unroll
                for (int r = 0; r < 4; ++r)
                    Qst[(size_t)(grb + r) * C_ + gc] = f2bf(acc[mi][ni][r]);
            } else {
                const int b = grb >> 10, tb = grb & 1023;
                const int h = gc >> 7,  d  = gc & 127;
                const size_t fb = (((size_t)(b * H_ + h)) * L_ + P_ + tb) * D_ + d;
                if (region == 0) {
#pragma unroll
                    for (int r = 0; r < 4; ++r) {
                        kout[fb + (size_t)r * D_] = acc[mi][ni][r];
                        kb[fb + (size_t)r * D_]   = f2bf(acc[mi][ni][r]);
                    }
                } else {
#pragma unroll
                    for (int r = 0; r < 4; ++r) vout[fb + (size_t)r * D_] = acc[mi][ni][r];
                    const size_t tb2 = (((size_t)(b * H_ + h)) * D_ + d) * L_ + P_ + tb;
                    *(u16x4*)&vbT[tb2] = u16x4{
                        f2bf(acc[mi][ni][0]), f2bf(acc[mi][ni][1]),
                        f2bf(acc[mi][ni][2]), f2bf(acc[mi][ni][3])};
                }
            }
        }
    }
}

// ---------------------------------------------------------------------------
// Plain NT GEMM, same pipeline (unchanged). MODE 0: bf16 out. MODE 2: f32+bias.
template <int MODE>
__global__ __launch_bounds__(256) void gemm128(
        const u16* __restrict__ A, const u16* __restrict__ Bw,
        float* __restrict__ outf, u16* __restrict__ outb,
        const float* __restrict__ bias) {
    __shared__ u16 As[3][128 * 32];
    __shared__ u16 Bs[3][128 * 32];
    const int tid  = threadIdx.x;
    const int wave = tid >> 6;
    const int lane = tid & 63;
    const int m0 = blockIdx.y * 128;
    const int n0 = blockIdx.x * 128;

    f32x4 acc[4][4];
#pragma unroll
    for (int i = 0; i < 4; ++i)
#pragma unroll
        for (int j = 0; j < 4; ++j) acc[i][j] = f32x4{0.f, 0.f, 0.f, 0.f};

    const int srow = lane >> 2;
    const int scol = (lane & 3) * 8;
    const int q0 = wave * 2, q1 = wave * 2 + 1;
    const u16* A0 = A  + (size_t)(m0 + q0 * 16 + srow) * C_ + scol;
    const u16* A1 = A  + (size_t)(m0 + q1 * 16 + srow) * C_ + scol;
    const u16* B0 = Bw + (size_t)(n0 + q0 * 16 + srow) * C_ + scol;
    const u16* B1 = Bw + (size_t)(n0 + q1 * 16 + srow) * C_ + scol;

    const int frow = lane & 15;
    const int fko  = (lane >> 4) * 8;
    const int wr = (wave >> 1) * 64;
    const int wc = (wave & 1) * 64;

    u16 *Ac = &As[0][0], *An = &As[1][0], *Af = &As[2][0];
    u16 *Bc = &Bs[0][0], *Bn = &Bs[1][0], *Bf = &Bs[2][0];

    gload_lds16(A0,      Ac + q0 * 512);
    gload_lds16(A1,      Ac + q1 * 512);
    gload_lds16(B0,      Bc + q0 * 512);
    gload_lds16(B1,      Bc + q1 * 512);
    gload_lds16(A0 + 32, An + q0 * 512);
    gload_lds16(A1 + 32, An + q1 * 512);
    gload_lds16(B0 + 32, Bn + q0 * 512);
    gload_lds16(B1 + 32, Bn + q1 * 512);

    for (int kt = 0; kt < C_ - 32; kt += 32) {
        asm volatile("s_waitcnt vmcnt(4)" ::: "memory");
        __builtin_amdgcn_s_barrier();
        asm volatile("" ::: "memory");
        if (kt + 64 < C_) {
            gload_lds16(A0 + kt + 64, Af + q0 * 512);
            gload_lds16(A1 + kt + 64, Af + q1 * 512);
            gload_lds16(B0 + kt + 64, Bf + q0 * 512);
            gload_lds16(B1 + kt + 64, Bf + q1 * 512);
        }
        short8 af[4], bf[4];
#pragma unroll
        for (int i = 0; i < 4; ++i) {
            af[i] = *(const short8*)&Ac[(wr + i * 16 + frow) * 32 + fko];
            bf[i] = *(const short8*)&Bc[(wc + i * 16 + frow) * 32 + fko];
        }
#pragma unroll
        for (int mi = 0; mi < 4; ++mi)
#pragma unroll
            for (int ni = 0; ni < 4; ++ni)
                acc[mi][ni] = __builtin_amdgcn_mfma_f32_16x16x32_bf16(
                    af[mi], bf[ni], acc[mi][ni], 0, 0, 0);
        u16* t;
        t = Ac; Ac = An; An = Af; Af = t;
        t = Bc; Bc = Bn; Bn = Bf; Bf = t;
    }
    {
        asm volatile("s_waitcnt vmcnt(0)" ::: "memory");
        __builtin_amdgcn_s_barrier();
        asm volatile("" ::: "memory");
        short8 af[4], bf[4];
#pragma unroll
        for (int i = 0; i < 4; ++i) {
            af[i] = *(const short8*)&Ac[(wr + i * 16 + frow) * 32 + fko];
            bf[i] = *(const short8*)&Bc[(wc + i * 16 + frow) * 32 + fko];
        }
#pragma unroll
        for (int mi = 0; mi < 4; ++mi)
#pragma unroll
            for (int ni = 0; ni < 4; ++ni)
                acc[mi][ni] = __builtin_amdgcn_mfma_f32_16x16x32_bf16(
                    af[mi], bf[ni], acc[mi][ni], 0, 0, 0);
    }

    const int ccol = lane & 15;
    const int crb  = (lane >> 4) * 4;
#pragma unroll
    for (int mi = 0; mi < 4; ++mi) {
#pragma unroll
        for (int ni = 0; ni < 4; ++ni) {
            const int gc  = n0 + wc + ni * 16 + ccol;
            const int grb = m0 + wr + mi * 16 + crb;
            if (MODE == 0) {
#pragma unroll
                for (int r = 0; r < 4; ++r)
                    outb[(size_t)(grb + r) * C_ + gc] = f2bf(acc[mi][ni][r]);
            } else {
                const float ba = bias[gc];
#pragma unroll
                for (int r = 0; r < 4; ++r)
                    outf[(size_t)(grb + r) * C_ + gc] = acc[mi][ni][r] + ba;
            }
        }
    }
}

// ---------------------------------------------------------------------------
// MFMA flash attention with T14 async-STAGE: K/V chunk ch+1 loaded to REGISTERS
// during chunk ch's compute; ds_write at next iteration top. Raw s_barrier +
// lgkmcnt-only waits (no vmcnt drain) keep the prefetch in flight.
#define NEG_BIG -30000.f
__global__ __launch_bounds__(256) void attn_kernel(
        const u16* __restrict__ Q, const u16* __restrict__ Kb,
        const u16* __restrict__ VT, u16* __restrict__ O) {
    __shared__ u16 Qs[64 * 128];   // [qrow][d]   swizzled
    __shared__ u16 Ks[64 * 128];   // [key][d]    swizzled
    __shared__ u16 Vs[128 * 64];   // [d][key]    swizzled (V^T)
    __shared__ u16 Ps[64][72];     // P tile

    const int tid  = threadIdx.x;
    const int wave = tid >> 6;
    const int lane = tid & 63;
    int       qt = blockIdx.x & 15;
    const int h  = (blockIdx.x >> 4) & 15;
    const int b  = blockIdx.x >> 8;
    if (b) qt = 15 - qt;                 // CU pair (c, c+256) sums to 49 chunks
    const int t0 = qt * 64;

    const u16* Kbase = Kb + (size_t)(b * H_ + h) * L_ * D_;
    const u16* Vbase = VT + (size_t)(b * H_ + h) * D_ * L_;

    // Stage Q tile (gload_lds, swizzled source) - issued first, oldest in vmcnt.
#pragma unroll
    for (int i = 0; i < 4; ++i) {
        int g   = (wave * 4 + i) * 64 + lane;   // 16B-block id 0..1023
        int row = g >> 4, blk = g & 15;
        int sb  = (blk & 8) | ((blk ^ row) & 7);
        gload_lds16(Q + ((size_t)(b * T_ + t0 + row)) * C_ + h * D_ + sb * 8,
                    &Qs[(wave * 4 + i) * 512]);
    }

    // Per-(i,lane) constant source offsets and LDS write pointers for K/V.
    int koff[4], voff[4];
    u16 *kdst[4], *vdst[4];
#pragma unroll
    for (int i = 0; i < 4; ++i) {
        int g = (wave * 4 + i) * 64 + lane;
        {   // K: row = key within chunk, 16 blocks/row
            int row = g >> 4, blk = g & 15;
            int sb  = (blk & 8) | ((blk ^ row) & 7);
            koff[i] = row * D_ + sb * 8;
            kdst[i] = &Ks[(wave * 4 + i) * 512 + lane * 8];
        }
        {   // V^T: row = d, 8 blocks/row
            int d  = g >> 3, cb = g & 7;
            int sb = (cb ^ d) & 7;
            voff[i] = d * L_ + sb * 8;
            vdst[i] = &Vs[(wave * 4 + i) * 512 + lane * 8];
        }
    }

    // Prefetch chunk 0 into registers (issued after Q's 4 gloads).
    u16x8 kreg[4], vreg[4];
#pragma unroll
    for (int i = 0; i < 4; ++i) {
        kreg[i] = *(const u16x8*)(Kbase + koff[i]);
        vreg[i] = *(const u16x8*)(Vbase + voff[i]);
    }
    // Wait ONLY the Q gloads (oldest 4 of 12 outstanding); K/V regs stay in flight.
    asm volatile("s_waitcnt vmcnt(8)" ::: "memory");

    const int frow = lane & 15;
    const int quad = lane >> 4;
    const int fko  = quad * 8;
    const int swz  = (frow & 7) << 3;

    f32x4 o_acc[8];
#pragma unroll
    for (int n = 0; n < 8; ++n) o_acc[n] = f32x4{0.f, 0.f, 0.f, 0.f};
    float m_i[4] = {NEG_BIG, NEG_BIG, NEG_BIG, NEG_BIG};
    float l_i[4] = {0.f, 0.f, 0.f, 0.f};
    const float scale = 0.08838834764831845f;   // 1/sqrt(128)

    const int nch = (P_ + t0 + 64) >> 6;
    const int wave_lim = P_ + t0 + wave * 16 + 15;

    for (int ch = 0; ch < nch; ++ch) {
        const int j0 = ch * 64;
        // Barrier A: all waves done reading Ks/Vs of prior chunk (their PV
        // ds_reads completed before their MFMAs). No count drain needed.
        asm volatile("" ::: "memory");
        __builtin_amdgcn_s_barrier();
        asm volatile("" ::: "memory");
        // Write staged regs to LDS (compiler auto-waits vmcnt on kreg/vreg —
        // those loads had a full chunk of compute to land).
#pragma unroll
        for (int i = 0; i < 4; ++i) *(u16x8*)kdst[i] = kreg[i];
#pragma unroll
        for (int i = 0; i < 4; ++i) *(u16x8*)vdst[i] = vreg[i];
        // Barrier B: LDS writes visible to all waves. lgkm-only drain.
        asm volatile("s_waitcnt lgkmcnt(0)" ::: "memory");
        __builtin_amdgcn_s_barrier();
        asm volatile("" ::: "memory");
        // Issue next-chunk loads; they hide under QK^T + softmax + PV.
        if (ch + 1 < nch) {
            const int jn = j0 + 64;
#pragma unroll
            for (int i = 0; i < 4; ++i) {
                kreg[i] = *(const u16x8*)(Kbase + (size_t)jn * D_ + koff[i]);
                vreg[i] = *(const u16x8*)(Vbase + jn + voff[i]);
            }
        }

        const bool active = (j0 <= wave_lim);

        if (active) {
            f32x4 st[4];
#pragma unroll
            for (int j = 0; j < 4; ++j) st[j] = f32x4{0.f, 0.f, 0.f, 0.f};
            __builtin_amdgcn_s_setprio(1);
#pragma unroll
            for (int kt = 0; kt < 4; ++kt) {
                short8 a = *(const short8*)&Qs[(wave * 16 + frow) * 128 +
                                               ((kt * 32 + fko) ^ swz)];
#pragma unroll
                for (int j = 0; j < 4; ++j) {
                    short8 kf = *(const short8*)&Ks[(j * 16 + frow) * 128 +
                                                    ((kt * 32 + fko) ^ swz)];
                    st[j] = __builtin_amdgcn_mfma_f32_16x16x32_bf16(a, kf, st[j], 0, 0, 0);
                }
            }
            __builtin_amdgcn_s_setprio(0);

            // Online softmax. exp underflow handles masking (m_i > NEG_BIG
            // after chunk 0, which is fully unmasked for every row).
            const bool full = (j0 + 63 <= P_ + t0 + wave * 16);  // wave-uniform
#pragma unroll
            for (int r = 0; r < 4; ++r) {
                const int lim = P_ + t0 + wave * 16 + quad * 4 + r;
                float sv[4];
                float mx = NEG_BIG;
#pragma unroll
                for (int j = 0; j < 4; ++j) {
                    float s = st[j][r] * scale;
                    if (!full) {
                        int jg = j0 + j * 16 + frow;
                        s = (jg <= lim) ? s : NEG_BIG;
                    }
                    sv[j] = s;
                    mx = fmaxf(mx, s);
                }
#pragma unroll
                for (int sft = 1; sft <= 8; sft <<= 1)
                    mx = fmaxf(mx, __shfl_xor(mx, sft, 64));
                float m_new = fmaxf(m_i[r], mx);
                float alpha = __expf(m_i[r] - m_new);   // arg <= 0 by construction
                float rs = 0.f;
#pragma unroll
                for (int j = 0; j < 4; ++j) {
                    float p = __expf(sv[j] - m_new);    // masked -> underflow 0
                    sv[j] = p;
                    rs += p;
                }
#pragma unroll
                for (int sft = 1; sft <= 8; sft <<= 1)
                    rs += __shfl_xor(rs, sft, 64);
                l_i[r] = l_i[r] * alpha + rs;
                m_i[r] = m_new;
#pragma unroll
                for (int n = 0; n < 8; ++n) o_acc[n][r] *= alpha;
#pragma unroll
                for (int j = 0; j < 4; ++j)
                    Ps[wave * 16 + quad * 4 + r][j * 16 + frow] = f2bf(sv[j]);
            }
        }
        // Ps barrier: lgkm-only drain (keeps K/V prefetch in flight).
        asm volatile("s_waitcnt lgkmcnt(0)" ::: "memory");
        __builtin_amdgcn_s_barrier();
        asm volatile("" ::: "memory");

        if (active) {
            __builtin_amdgcn_s_setprio(1);
#pragma unroll
            for (int kt2 = 0; kt2 < 2; ++kt2) {
                short8 a = *(const short8*)&Ps[wave * 16 + frow][kt2 * 32 + fko];
#pragma unroll
                for (int n = 0; n < 8; ++n) {
                    short8 vf = *(const short8*)&Vs[(n * 16 + frow) * 64 +
                                                    ((kt2 * 32 + fko) ^ swz)];
                    o_acc[n] = __builtin_amdgcn_mfma_f32_16x16x32_bf16(a, vf, o_acc[n], 0, 0, 0);
                }
            }
            __builtin_amdgcn_s_setprio(0);
        }
    }

    // Epilogue: O /= l, store bf16 [B,T,C]
#pragma unroll
    for (int r = 0; r < 4; ++r) {
        float rl = 1.f / fmaxf(l_i[r], 1e-30f);
        int t = t0 + wave * 16 + quad * 4 + r;
#pragma unroll
        for (int n = 0; n < 8; ++n) {
            float v = o_acc[n][r] * rl;
            O[((size_t)(b * T_ + t)) * C_ + h * D_ + n * 16 + frow] = f2bf(v);
        }
    }
}

// ---------------------------------------------------------------------------
extern "C" void kernel_launch(void* const* d_in, const int* in_sizes, int n_in,
                              void* d_out, int out_size, void* d_ws, size_t ws_size,
                              hipStream_t stream) {
    const float* x      = (const float*)d_in[0];
    const float* past_k = (const float*)d_in[1];
    const float* past_v = (const float*)d_in[2];
    const float* Wk     = (const float*)d_in[3];
    const float* Wq     = (const float*)d_in[4];
    const float* Wv     = (const float*)d_in[5];
    const float* Wp     = (const float*)d_in[6];
    const float* bp     = (const float*)d_in[7];

    float* out  = (float*)d_out;             // [B,T,C]    16 MB
    float* kout = out + 4194304;             // [B,H,L,D]  32 MB
    float* vout = kout + 8388608;            // [B,H,L,D]  32 MB

    // d_out scratch (dead until final GEMM writes out):
    u16* Qst = (u16*)d_out;                          //  8 MB bf16 Q
    u16* xb  = (u16*)((char*)d_out + (8u << 20));    //  8 MB bf16 x
    // d_ws (proven >= 48 MiB):
    u16* OstWq = (u16*)d_ws;                         //  8 MB: Wq bf16, then attn out
    u16* kb    = (u16*)((char*)d_ws + (8u  << 20));  // 16 MB bf16 K cache [B,H,L,D]
    u16* vbT   = (u16*)((char*)d_ws + (24u << 20));  // 16 MB bf16 V^T cache [B,H,D,L]
    u16* wbKP  = (u16*)((char*)d_ws + (40u << 20));  //  8 MB: Wk bf16 (then Wp if !bigws)
    const bool fused = ws_size >= (size_t)(56u << 20);
    const bool bigws = ws_size >= (size_t)(64u << 20);
    u16* wbV = fused ? (u16*)((char*)d_ws + (48u << 20))
                     : Qst;   // fallback: Wv parked in Qst slot (dead until Q-GEMM)
    u16* wbP = bigws ? (u16*)((char*)d_ws + (56u << 20)) : wbKP;

    prep_kernel<<<bigws ? 15360 : 13312, 256, 0, stream>>>(
        x, Wk, Wv, Wq, Wp,
        (const float4*)past_k, (const float4*)past_v,
        xb, wbKP, wbV, OstWq, bigws ? wbP : nullptr,
        (float4*)kout, (float4*)vout, (u16x4*)kb, vbT);

    if (fused) {
        dim3 g(48, 16);   // K | V | Q regions, 768 blocks (~3/CU)
        gemm_qkv<<<g, 256, 0, stream>>>(xb, wbKP, wbV, OstWq,
                                        kout, vout, kb, vbT, Qst);
    } else {
        dim3 gkv(32, 16); // K | V regions, 512 blocks (~2/CU)
        gemm_qkv<<<gkv, 256, 0, stream>>>(xb, wbKP, wbV, OstWq,
                                          kout, vout, kb, vbT, Qst);
        dim3 gq(16, 16);
        gemm128<0><<<gq, 256, 0, stream>>>(xb, OstWq, nullptr, Qst, nullptr);
    }

    attn_kernel<<<512, 256, 0, stream>>>(Qst, kb, vbT, OstWq);

    if (!bigws) convert_bf16_kernel<<<2048, 256, 0, stream>>>(Wp, wbKP);
    dim3 gp(16, 16);
    gemm128<2><<<gp, 256, 0, stream>>>(OstWq, wbP, out, nullptr, bp);
}